// Round 4
// baseline (706.870 us; speedup 1.0000x reference)
//
#include <hip/hip_runtime.h>

#define NB 8
#define NC 256
#define NHW 1024   // H*W
#define NL 4
#define NG 4
#define NK 2048
#define ND 64      // C/G

#define RS 68      // r_lds row stride (floats)
#define CS 72      // (fallback kernel) codebook LDS row stride (halfs)

typedef __attribute__((ext_vector_type(8))) _Float16 f16x8;
typedef __attribute__((ext_vector_type(4))) _Float16 f16x4;
typedef __attribute__((ext_vector_type(4))) float    f32x4;

// fp16 hi/lo split: v = h + l + O(2^-24 v). Products h*h etc are exact in fp32.
__device__ __forceinline__ void fsplit(float v, _Float16& h, _Float16& l) {
    _Float16 hh = (_Float16)v;
    h = hh;
    l = (_Float16)(v - (float)hh);
}

// ---------------- fast path: prep kernel ----------------
// Per 16-codeword tile: 4 fragments (hiC0, hiC1, loC0, loC1), each 64 lanes x
// 8 halfs, lane-linear (one dwordx4 per lane in the main kernel). Fused cn.
__global__ void cq_prep_kernel(const float* __restrict__ cb,
                               _Float16* __restrict__ wfrag,
                               float* __restrict__ cn) {
    int wv   = (blockIdx.x * 256 + threadIdx.x) >> 6;  // tile id 0..2047
    int lane = threadIdx.x & 63;
    int l4 = lane & 15, l16 = lane >> 4;
    int lg = wv >> 7, kt = wv & 127;
    int k  = kt * 16 + l4;
    const float* src = cb + ((size_t)lg * NK + k) * ND;

    float4 a0 = *(const float4*)(src + l16 * 8);
    float4 a1 = *(const float4*)(src + l16 * 8 + 4);
    float4 b0 = *(const float4*)(src + 32 + l16 * 8);
    float4 b1 = *(const float4*)(src + 32 + l16 * 8 + 4);

    f16x8 h0, lo0, h1, lo1;
    _Float16 h, lo;
    fsplit(a0.x,h,lo); h0[0]=h; lo0[0]=lo;  fsplit(a0.y,h,lo); h0[1]=h; lo0[1]=lo;
    fsplit(a0.z,h,lo); h0[2]=h; lo0[2]=lo;  fsplit(a0.w,h,lo); h0[3]=h; lo0[3]=lo;
    fsplit(a1.x,h,lo); h0[4]=h; lo0[4]=lo;  fsplit(a1.y,h,lo); h0[5]=h; lo0[5]=lo;
    fsplit(a1.z,h,lo); h0[6]=h; lo0[6]=lo;  fsplit(a1.w,h,lo); h0[7]=h; lo0[7]=lo;
    fsplit(b0.x,h,lo); h1[0]=h; lo1[0]=lo;  fsplit(b0.y,h,lo); h1[1]=h; lo1[1]=lo;
    fsplit(b0.z,h,lo); h1[2]=h; lo1[2]=lo;  fsplit(b0.w,h,lo); h1[3]=h; lo1[3]=lo;
    fsplit(b1.x,h,lo); h1[4]=h; lo1[4]=lo;  fsplit(b1.y,h,lo); h1[5]=h; lo1[5]=lo;
    fsplit(b1.z,h,lo); h1[6]=h; lo1[6]=lo;  fsplit(b1.w,h,lo); h1[7]=h; lo1[7]=lo;

    _Float16* outp = wfrag + (size_t)wv * 2048;   // tile = 4096 B
    *(f16x8*)(outp +    0 + lane * 8) = h0;
    *(f16x8*)(outp +  512 + lane * 8) = h1;
    *(f16x8*)(outp + 1024 + lane * 8) = lo0;
    *(f16x8*)(outp + 1536 + lane * 8) = lo1;

    float s = a0.x*a0.x + a0.y*a0.y + a0.z*a0.z + a0.w*a0.w
            + a1.x*a1.x + a1.y*a1.y + a1.z*a1.z + a1.w*a1.w
            + b0.x*b0.x + b0.y*b0.y + b0.z*b0.z + b0.w*b0.w
            + b1.x*b1.x + b1.y*b1.y + b1.z*b1.z + b1.w*b1.w;
    s += __shfl_xor(s, 16, 64);
    s += __shfl_xor(s, 32, 64);
    if (l16 == 0) cn[(size_t)lg * NK + k] = 0.5f * s;
}

// ---------------- fast path: main kernel v4 ----------------
struct Frag { f16x8 h0, h1, l0, l1; };

__device__ __forceinline__ void load_stage(const _Float16* fb, const float* cnl,
                                           int kl, int lane, int s,
                                           Frag& F, float& cv) {
    const _Float16* p = fb + (size_t)s * 2048 + lane * 8;
    F.h0 = *(const f16x8*)(p);
    F.h1 = *(const f16x8*)(p + 512);
    F.l0 = *(const f16x8*)(p + 1024);
    F.l1 = *(const f16x8*)(p + 1536);
    cv = cnl[kl + s * 16];
}

__device__ __forceinline__ void do_stage(const Frag& F, float cv, int s,
                                         const f16x8 (&ah)[2][2], const f16x8 (&al)[2][2],
                                         const f32x4& Z,
                                         float (&minv)[2][4], int (&mini)[2][4]) {
    f32x4 a0, a1;
    a0 = __builtin_amdgcn_mfma_f32_16x16x32_f16(ah[0][0], F.h0, Z, 0, 0, 0);
    a1 = __builtin_amdgcn_mfma_f32_16x16x32_f16(ah[1][0], F.h0, Z, 0, 0, 0);
    a0 = __builtin_amdgcn_mfma_f32_16x16x32_f16(ah[0][1], F.h1, a0, 0, 0, 0);
    a1 = __builtin_amdgcn_mfma_f32_16x16x32_f16(ah[1][1], F.h1, a1, 0, 0, 0);
    a0 = __builtin_amdgcn_mfma_f32_16x16x32_f16(ah[0][0], F.l0, a0, 0, 0, 0);
    a1 = __builtin_amdgcn_mfma_f32_16x16x32_f16(ah[1][0], F.l0, a1, 0, 0, 0);
    a0 = __builtin_amdgcn_mfma_f32_16x16x32_f16(ah[0][1], F.l1, a0, 0, 0, 0);
    a1 = __builtin_amdgcn_mfma_f32_16x16x32_f16(ah[1][1], F.l1, a1, 0, 0, 0);
    a0 = __builtin_amdgcn_mfma_f32_16x16x32_f16(al[0][0], F.h0, a0, 0, 0, 0);
    a1 = __builtin_amdgcn_mfma_f32_16x16x32_f16(al[1][0], F.h0, a1, 0, 0, 0);
    a0 = __builtin_amdgcn_mfma_f32_16x16x32_f16(al[0][1], F.h1, a0, 0, 0, 0);
    a1 = __builtin_amdgcn_mfma_f32_16x16x32_f16(al[1][1], F.h1, a1, 0, 0, 0);
#pragma unroll
    for (int j = 0; j < 4; ++j) {
        float s0 = a0[j] + cv;
        bool lt0 = s0 < minv[0][j];
        minv[0][j] = lt0 ? s0 : minv[0][j];
        mini[0][j] = lt0 ? s : mini[0][j];      // s is compile-time const
        float s1 = a1[j] + cv;
        bool lt1 = s1 < minv[1][j];
        minv[1][j] = lt1 ? s1 : minv[1][j];
        mini[1][j] = lt1 ? s : mini[1][j];
    }
}

// 512 blocks x 512 threads (2 blocks/CU, 4 waves/SIMD). Block owns 64 rows;
// wave = (row-half, k-quarter): 32 rows x 512 cw. No barriers in the k-loop.
__global__ __launch_bounds__(512, 4) void cq_main4_kernel(
    const float* __restrict__ x, const float* __restrict__ cb,
    const _Float16* __restrict__ wfrag, const float* __restrict__ cn,
    float* __restrict__ out)
{
    __shared__ float r_lds[64][RS];
    __shared__ float mv_lds[4][64];
    __shared__ int   mi_lds[4][64];
    __shared__ int   ks_lds[64];

    const int tid = threadIdx.x;
    const int blk = blockIdx.x;       // 512 = 8b * 4g * 16nt
    const int nt  = blk & 15;
    const int g   = (blk >> 4) & 3;
    const int b   = blk >> 6;
    const int n0  = nt * 64;

    const float* xb = x + ((size_t)(b * NC + g * ND)) * NHW + n0;
#pragma unroll
    for (int dd = 0; dd < 2; ++dd) {
        int d = (tid >> 4) + dd * 32;
        int n = (tid & 15) * 4;
        float4 xv = *(const float4*)(&xb[(size_t)d * NHW + n]);
        r_lds[n + 0][d] = xv.x; r_lds[n + 1][d] = xv.y;
        r_lds[n + 2][d] = xv.z; r_lds[n + 3][d] = xv.w;
    }
    __syncthreads();

    const int lane = tid & 63;
    const int w    = tid >> 6;        // 8 waves
    const int rh   = w & 1;           // row half
    const int kq   = w >> 1;          // k quarter
    const int l4   = lane & 15;
    const int l16  = lane >> 4;
    const int kbase = kq * 512;

    const f32x4 Z = {0.f, 0.f, 0.f, 0.f};

    for (int l = 0; l < NL; ++l) {
        const float* cbl_g = cb + (size_t)(l * NG + g) * NK * ND;
        const float* cnl   = cn + (size_t)(l * NG + g) * NK;
        const _Float16* fb = wfrag + ((size_t)(l * NG + g) * 128 + kq * 32) * 2048;
        const int kl = kbase + l4;

        // negated hi/lo A fragments: rows rh*32+ns*16+l4, d = c*32+l16*8+j
        f16x8 ah[2][2], al[2][2];
#pragma unroll
        for (int ns = 0; ns < 2; ++ns) {
#pragma unroll
            for (int c = 0; c < 2; ++c) {
                const float* rp = &r_lds[rh * 32 + ns * 16 + l4][c * 32 + l16 * 8];
                float4 v0 = *(const float4*)(rp);
                float4 v1 = *(const float4*)(rp + 4);
                _Float16 h, lo; f16x8 hv, lv;
                fsplit(-v0.x,h,lo); hv[0]=h; lv[0]=lo;
                fsplit(-v0.y,h,lo); hv[1]=h; lv[1]=lo;
                fsplit(-v0.z,h,lo); hv[2]=h; lv[2]=lo;
                fsplit(-v0.w,h,lo); hv[3]=h; lv[3]=lo;
                fsplit(-v1.x,h,lo); hv[4]=h; lv[4]=lo;
                fsplit(-v1.y,h,lo); hv[5]=h; lv[5]=lo;
                fsplit(-v1.z,h,lo); hv[6]=h; lv[6]=lo;
                fsplit(-v1.w,h,lo); hv[7]=h; lv[7]=lo;
                ah[ns][c] = hv; al[ns][c] = lv;
            }
        }

        float minv[2][4];
        int   mini[2][4];
#pragma unroll
        for (int i = 0; i < 2; ++i)
#pragma unroll
            for (int j = 0; j < 4; ++j) { minv[i][j] = 3.4e38f; mini[i][j] = 0; }

        // register double-buffer, 2 stages/iter, no copies
        Frag X, Y; float cvX, cvY;
        load_stage(fb, cnl, kl, lane, 0, X, cvX);
#pragma unroll
        for (int i = 0; i < 16; ++i) {
            load_stage(fb, cnl, kl, lane, 2 * i + 1, Y, cvY);
            do_stage(X, cvX, 2 * i, ah, al, Z, minv, mini);
            if (i < 15) load_stage(fb, cnl, kl, lane, 2 * i + 2, X, cvX);
            do_stage(Y, cvY, 2 * i + 1, ah, al, Z, minv, mini);
        }

        // reconstruct k, reduce over the 16 k-lanes (ties -> lower k)
        int kk[2][4];
#pragma unroll
        for (int ns = 0; ns < 2; ++ns)
#pragma unroll
            for (int j = 0; j < 4; ++j)
                kk[ns][j] = kbase + mini[ns][j] * 16 + l4;
#pragma unroll
        for (int m = 1; m < 16; m <<= 1) {
#pragma unroll
            for (int ns = 0; ns < 2; ++ns)
#pragma unroll
                for (int j = 0; j < 4; ++j) {
                    float ov = __shfl_xor(minv[ns][j], m, 64);
                    int   oi = __shfl_xor(kk[ns][j], m, 64);
                    if (ov < minv[ns][j] || (ov == minv[ns][j] && oi < kk[ns][j])) {
                        minv[ns][j] = ov; kk[ns][j] = oi;
                    }
                }
        }
        if (l4 == 0) {
#pragma unroll
            for (int ns = 0; ns < 2; ++ns)
#pragma unroll
                for (int j = 0; j < 4; ++j) {
                    int row = rh * 32 + ns * 16 + l16 * 4 + j;  // C/D row map
                    mv_lds[kq][row] = minv[ns][j];
                    mi_lds[kq][row] = kk[ns][j];
                }
        }
        __syncthreads();
        if (tid < 64) {   // combine 4 quarters ascending (tie -> lower k)
            float bv = mv_lds[0][tid]; int bi = mi_lds[0][tid];
#pragma unroll
            for (int q = 1; q < 4; ++q) {
                float v = mv_lds[q][tid];
                if (v < bv) { bv = v; bi = mi_lds[q][tid]; }
            }
            ks_lds[tid] = bi;
        }
        __syncthreads();

        // r -= cb[k*]  (exact fp32, rows L2-hot)
        {
            int row = tid >> 3, dc = (tid & 7) * 8;
            int kw = ks_lds[row];
            const float* qp = cbl_g + (size_t)kw * ND + dc;
#pragma unroll
            for (int i = 0; i < 2; ++i) {
                float4 q  = *(const float4*)(qp + i * 4);
                float* rp = &r_lds[row][dc + i * 4];
                float4 rv = *(float4*)rp;
                rv.x -= q.x; rv.y -= q.y; rv.z -= q.z; rv.w -= q.w;
                *(float4*)rp = rv;
            }
        }
        __syncthreads();
    }

    // out = x - r_final
    float* ob = out + ((size_t)(b * NC + g * ND)) * NHW + n0;
#pragma unroll
    for (int dd = 0; dd < 2; ++dd) {
        int d = (tid >> 4) + dd * 32;
        int n = (tid & 15) * 4;
        float4 xv = *(const float4*)(&xb[(size_t)d * NHW + n]);
        float4 ov;
        ov.x = xv.x - r_lds[n + 0][d];
        ov.y = xv.y - r_lds[n + 1][d];
        ov.z = xv.z - r_lds[n + 2][d];
        ov.w = xv.w - r_lds[n + 3][d];
        *(float4*)(&ob[(size_t)d * NHW + n]) = ov;
    }
}

// ---------------- fallback path (round-2 kernels, 128 KB ws) ----------------
__global__ void cq_cnorm_kernel(const float* __restrict__ cb, float* __restrict__ cn) {
    int idx = blockIdx.x * 256 + threadIdx.x;
    const float4* p = reinterpret_cast<const float4*>(cb + (size_t)idx * ND);
    float s = 0.f;
#pragma unroll
    for (int i = 0; i < ND / 4; ++i) {
        float4 v = p[i];
        s += v.x * v.x + v.y * v.y + v.z * v.z + v.w * v.w;
    }
    cn[idx] = 0.5f * s;
}

__global__ __launch_bounds__(256, 1) void cq_main_kernel(
    const float* __restrict__ x, const float* __restrict__ cb,
    const float* __restrict__ cn, float* __restrict__ out)
{
    __shared__ float    r_lds[128][RS];
    __shared__ _Float16 cbh_lds[2][128][CS];
    __shared__ _Float16 cbl_lds[2][128][CS];
    __shared__ float    mv_lds[2][128];
    __shared__ int      mi_lds[2][128];
    __shared__ int      ks_lds[128];

    const int tid = threadIdx.x;
    const int blk = blockIdx.x;
    const int nt  = blk & 7;
    const int bg  = blk >> 3;
    const int g   = bg & 3;
    const int b   = bg >> 2;
    const int n0  = nt * 128;

    const float* xb = x + ((size_t)(b * NC + g * ND)) * NHW + n0;
#pragma unroll
    for (int dd = 0; dd < 8; ++dd) {
        int d = (tid >> 5) + dd * 8;
        int n = (tid & 31) * 4;
        float4 xv = *reinterpret_cast<const float4*>(&xb[(size_t)d * NHW + n]);
        r_lds[n + 0][d] = xv.x; r_lds[n + 1][d] = xv.y;
        r_lds[n + 2][d] = xv.z; r_lds[n + 3][d] = xv.w;
    }

    const int lane = tid & 63;
    const int wid  = tid >> 6;
    const int rg   = wid & 1;
    const int kh   = wid >> 1;
    const int l4   = lane & 15;
    const int l16  = lane >> 4;

    __syncthreads();

    for (int l = 0; l < NL; ++l) {
        const float* cbl_g = cb + (size_t)(l * NG + g) * NK * ND;
        const float* cnl   = cn + (size_t)(l * NG + g) * NK;

        f16x8 ah[4][2], al[4][2];
#pragma unroll
        for (int ns = 0; ns < 4; ++ns) {
#pragma unroll
            for (int c = 0; c < 2; ++c) {
                const float* rp = &r_lds[rg * 64 + ns * 16 + l4][c * 32 + l16 * 8];
                float4 v0 = *reinterpret_cast<const float4*>(rp);
                float4 v1 = *reinterpret_cast<const float4*>(rp + 4);
                _Float16 h, lo; f16x8 hv, lv;
                fsplit(-v0.x, h, lo); hv[0] = h; lv[0] = lo;
                fsplit(-v0.y, h, lo); hv[1] = h; lv[1] = lo;
                fsplit(-v0.z, h, lo); hv[2] = h; lv[2] = lo;
                fsplit(-v0.w, h, lo); hv[3] = h; lv[3] = lo;
                fsplit(-v1.x, h, lo); hv[4] = h; lv[4] = lo;
                fsplit(-v1.y, h, lo); hv[5] = h; lv[5] = lo;
                fsplit(-v1.z, h, lo); hv[6] = h; lv[6] = lo;
                fsplit(-v1.w, h, lo); hv[7] = h; lv[7] = lo;
                ah[ns][c] = hv; al[ns][c] = lv;
            }
        }

        float minv[4][4];
        int   mini[4][4];
#pragma unroll
        for (int i = 0; i < 4; ++i)
#pragma unroll
            for (int j = 0; j < 4; ++j) { minv[i][j] = 3.4e38f; mini[i][j] = 0; }

        float4 sreg[8];
#pragma unroll
        for (int p = 0; p < 8; ++p) {
            int kk = p * 16 + (tid >> 4);
            int kg = (kk < 64) ? kk : (1024 - 64 + kk);
            sreg[p] = *reinterpret_cast<const float4*>(&cbl_g[(size_t)kg * ND + (tid & 15) * 4]);
        }
#pragma unroll
        for (int p = 0; p < 8; ++p) {
            int kk = p * 16 + (tid >> 4);
            float4 v = sreg[p];
            _Float16 h, lo; f16x4 hv, lv;
            fsplit(v.x, h, lo); hv[0] = h; lv[0] = lo;
            fsplit(v.y, h, lo); hv[1] = h; lv[1] = lo;
            fsplit(v.z, h, lo); hv[2] = h; lv[2] = lo;
            fsplit(v.w, h, lo); hv[3] = h; lv[3] = lo;
            *reinterpret_cast<f16x4*>(&cbh_lds[0][kk][(tid & 15) * 4]) = hv;
            *reinterpret_cast<f16x4*>(&cbl_lds[0][kk][(tid & 15) * 4]) = lv;
        }

        for (int s = 0; s < 16; ++s) {
            __syncthreads();

            if (s < 15) {
#pragma unroll
                for (int p = 0; p < 8; ++p) {
                    int kk = p * 16 + (tid >> 4);
                    int kg = (kk < 64) ? ((s + 1) * 64 + kk) : (1024 + (s + 1) * 64 + (kk - 64));
                    sreg[p] = *reinterpret_cast<const float4*>(&cbl_g[(size_t)kg * ND + (tid & 15) * 4]);
                }
            }

            const int buf = s & 1;
            for (int ks = 0; ks < 4; ++ks) {
                int lrow = kh * 64 + ks * 16 + l4;
                int kabs = kh * 1024 + s * 64 + ks * 16 + l4;
                f16x8 bh0 = *reinterpret_cast<const f16x8*>(&cbh_lds[buf][lrow][l16 * 8]);
                f16x8 bh1 = *reinterpret_cast<const f16x8*>(&cbh_lds[buf][lrow][32 + l16 * 8]);
                f16x8 bl0 = *reinterpret_cast<const f16x8*>(&cbl_lds[buf][lrow][l16 * 8]);
                f16x8 bl1 = *reinterpret_cast<const f16x8*>(&cbl_lds[buf][lrow][32 + l16 * 8]);
                float cnv = cnl[kabs];
                f32x4 acc[4];
#pragma unroll
                for (int ns = 0; ns < 4; ++ns) acc[ns] = (f32x4){cnv, cnv, cnv, cnv};
#pragma unroll
                for (int ns = 0; ns < 4; ++ns) {
                    acc[ns] = __builtin_amdgcn_mfma_f32_16x16x32_f16(ah[ns][0], bh0, acc[ns], 0, 0, 0);
                    acc[ns] = __builtin_amdgcn_mfma_f32_16x16x32_f16(ah[ns][1], bh1, acc[ns], 0, 0, 0);
                    acc[ns] = __builtin_amdgcn_mfma_f32_16x16x32_f16(ah[ns][0], bl0, acc[ns], 0, 0, 0);
                    acc[ns] = __builtin_amdgcn_mfma_f32_16x16x32_f16(ah[ns][1], bl1, acc[ns], 0, 0, 0);
                    acc[ns] = __builtin_amdgcn_mfma_f32_16x16x32_f16(al[ns][0], bh0, acc[ns], 0, 0, 0);
                    acc[ns] = __builtin_amdgcn_mfma_f32_16x16x32_f16(al[ns][1], bh1, acc[ns], 0, 0, 0);
                }
#pragma unroll
                for (int ns = 0; ns < 4; ++ns)
#pragma unroll
                    for (int j = 0; j < 4; ++j) {
                        float sc = acc[ns][j];
                        bool lt = sc < minv[ns][j];
                        minv[ns][j] = lt ? sc : minv[ns][j];
                        mini[ns][j] = lt ? kabs : mini[ns][j];
                    }
            }

            if (s < 15) {
                const int nbuf = (s + 1) & 1;
#pragma unroll
                for (int p = 0; p < 8; ++p) {
                    int kk = p * 16 + (tid >> 4);
                    float4 v = sreg[p];
                    _Float16 h, lo; f16x4 hv, lv;
                    fsplit(v.x, h, lo); hv[0] = h; lv[0] = lo;
                    fsplit(v.y, h, lo); hv[1] = h; lv[1] = lo;
                    fsplit(v.z, h, lo); hv[2] = h; lv[2] = lo;
                    fsplit(v.w, h, lo); hv[3] = h; lv[3] = lo;
                    *reinterpret_cast<f16x4*>(&cbh_lds[nbuf][kk][(tid & 15) * 4]) = hv;
                    *reinterpret_cast<f16x4*>(&cbl_lds[nbuf][kk][(tid & 15) * 4]) = lv;
                }
            }
        }

#pragma unroll
        for (int m = 1; m < 16; m <<= 1) {
#pragma unroll
            for (int ns = 0; ns < 4; ++ns)
#pragma unroll
                for (int j = 0; j < 4; ++j) {
                    float ov = __shfl_xor(minv[ns][j], m, 64);
                    int   oi = __shfl_xor(mini[ns][j], m, 64);
                    if (ov < minv[ns][j] || (ov == minv[ns][j] && oi < mini[ns][j])) {
                        minv[ns][j] = ov; mini[ns][j] = oi;
                    }
                }
        }
        if (l4 == 0) {
#pragma unroll
            for (int ns = 0; ns < 4; ++ns)
#pragma unroll
                for (int j = 0; j < 4; ++j) {
                    int row = rg * 64 + ns * 16 + l16 * 4 + j;
                    mv_lds[kh][row] = minv[ns][j];
                    mi_lds[kh][row] = mini[ns][j];
                }
        }
        __syncthreads();
        if (tid < 128) {
            float v0 = mv_lds[0][tid], v1 = mv_lds[1][tid];
            ks_lds[tid] = (v1 < v0) ? mi_lds[1][tid] : mi_lds[0][tid];
        }
        __syncthreads();

        {
            int n  = tid >> 1;
            int db = (tid & 1) * 32;
            int kw = ks_lds[n];
            const float* qp = &cbl_g[(size_t)kw * ND + db];
#pragma unroll
            for (int i = 0; i < 8; ++i) {
                float4 q  = *reinterpret_cast<const float4*>(&qp[i * 4]);
                float* rp = &r_lds[n][db + i * 4];
                float4 rv = *reinterpret_cast<float4*>(rp);
                rv.x -= q.x; rv.y -= q.y; rv.z -= q.z; rv.w -= q.w;
                *reinterpret_cast<float4*>(rp) = rv;
            }
        }
        __syncthreads();
    }

    float* ob = out + ((size_t)(b * NC + g * ND)) * NHW + n0;
#pragma unroll
    for (int dd = 0; dd < 8; ++dd) {
        int d = (tid >> 5) + dd * 8;
        int n = (tid & 31) * 4;
        float4 xv = *reinterpret_cast<const float4*>(&xb[(size_t)d * NHW + n]);
        float4 ov;
        ov.x = xv.x - r_lds[n + 0][d];
        ov.y = xv.y - r_lds[n + 1][d];
        ov.z = xv.z - r_lds[n + 2][d];
        ov.w = xv.w - r_lds[n + 3][d];
        *reinterpret_cast<float4*>(&ob[(size_t)d * NHW + n]) = ov;
    }
}

extern "C" void kernel_launch(void* const* d_in, const int* in_sizes, int n_in,
                              void* d_out, int out_size, void* d_ws, size_t ws_size,
                              hipStream_t stream) {
    const float* x  = (const float*)d_in[0];   // [B, C, H, W]
    const float* cb = (const float*)d_in[1];   // [L, G, K, D]
    float* out = (float*)d_out;

    const size_t FRAG_BYTES = (size_t)NL * NG * NK * ND * 2 * 2;  // 8 MiB
    const size_t NEED = FRAG_BYTES + (size_t)NL * NG * NK * 4;    // + cn

    if (ws_size >= NEED) {
        _Float16* wfrag = (_Float16*)d_ws;
        float* cn = (float*)((char*)d_ws + FRAG_BYTES);
        cq_prep_kernel<<<512, 256, 0, stream>>>(cb, wfrag, cn);
        cq_main4_kernel<<<NB * NG * (NHW / 64), 512, 0, stream>>>(x, cb, wfrag, cn, out);
    } else {
        float* cn = (float*)d_ws;
        cq_cnorm_kernel<<<(NL * NG * NK) / 256, 256, 0, stream>>>(cb, cn);
        cq_main_kernel<<<NB * NG * (NHW / 128), 256, 0, stream>>>(x, cb, cn, out);
    }
}

// Round 5
// 242.139 us; speedup vs baseline: 2.9193x; 2.9193x over previous
//
#include <hip/hip_runtime.h>

#define NB 8
#define NC 256
#define NHW 1024   // H*W
#define NL 4
#define NG 4
#define NK 2048
#define ND 64      // C/G

#define RS 68      // r_lds row stride (floats)
#define CS 72      // (fallback kernel) codebook LDS row stride (halfs)

typedef __attribute__((ext_vector_type(8))) _Float16 f16x8;
typedef __attribute__((ext_vector_type(4))) _Float16 f16x4;
typedef __attribute__((ext_vector_type(4))) float    f32x4;

// fp16 hi/lo split: v = h + l + O(2^-24 v). Products h*h etc are exact in fp32.
__device__ __forceinline__ void fsplit(float v, _Float16& h, _Float16& l) {
    _Float16 hh = (_Float16)v;
    h = hh;
    l = (_Float16)(v - (float)hh);
}

// ---------------- fast path: prep kernel ----------------
// Per 16-codeword tile: 4 fragments (hiC0, hiC1, loC0, loC1), each 64 lanes x
// 8 halfs, lane-linear (one dwordx4 per lane in the main kernel). Fused cn.
__global__ void cq_prep_kernel(const float* __restrict__ cb,
                               _Float16* __restrict__ wfrag,
                               float* __restrict__ cn) {
    int wv   = (blockIdx.x * 256 + threadIdx.x) >> 6;  // tile id 0..2047
    int lane = threadIdx.x & 63;
    int l4 = lane & 15, l16 = lane >> 4;
    int lg = wv >> 7, kt = wv & 127;
    int k  = kt * 16 + l4;
    const float* src = cb + ((size_t)lg * NK + k) * ND;

    float4 a0 = *(const float4*)(src + l16 * 8);
    float4 a1 = *(const float4*)(src + l16 * 8 + 4);
    float4 b0 = *(const float4*)(src + 32 + l16 * 8);
    float4 b1 = *(const float4*)(src + 32 + l16 * 8 + 4);

    f16x8 h0, lo0, h1, lo1;
    _Float16 h, lo;
    fsplit(a0.x,h,lo); h0[0]=h; lo0[0]=lo;  fsplit(a0.y,h,lo); h0[1]=h; lo0[1]=lo;
    fsplit(a0.z,h,lo); h0[2]=h; lo0[2]=lo;  fsplit(a0.w,h,lo); h0[3]=h; lo0[3]=lo;
    fsplit(a1.x,h,lo); h0[4]=h; lo0[4]=lo;  fsplit(a1.y,h,lo); h0[5]=h; lo0[5]=lo;
    fsplit(a1.z,h,lo); h0[6]=h; lo0[6]=lo;  fsplit(a1.w,h,lo); h0[7]=h; lo0[7]=lo;
    fsplit(b0.x,h,lo); h1[0]=h; lo1[0]=lo;  fsplit(b0.y,h,lo); h1[1]=h; lo1[1]=lo;
    fsplit(b0.z,h,lo); h1[2]=h; lo1[2]=lo;  fsplit(b0.w,h,lo); h1[3]=h; lo1[3]=lo;
    fsplit(b1.x,h,lo); h1[4]=h; lo1[4]=lo;  fsplit(b1.y,h,lo); h1[5]=h; lo1[5]=lo;
    fsplit(b1.z,h,lo); h1[6]=h; lo1[6]=lo;  fsplit(b1.w,h,lo); h1[7]=h; lo1[7]=lo;

    _Float16* outp = wfrag + (size_t)wv * 2048;   // tile = 4096 B
    *(f16x8*)(outp +    0 + lane * 8) = h0;
    *(f16x8*)(outp +  512 + lane * 8) = h1;
    *(f16x8*)(outp + 1024 + lane * 8) = lo0;
    *(f16x8*)(outp + 1536 + lane * 8) = lo1;

    float s = a0.x*a0.x + a0.y*a0.y + a0.z*a0.z + a0.w*a0.w
            + a1.x*a1.x + a1.y*a1.y + a1.z*a1.z + a1.w*a1.w
            + b0.x*b0.x + b0.y*b0.y + b0.z*b0.z + b0.w*b0.w
            + b1.x*b1.x + b1.y*b1.y + b1.z*b1.z + b1.w*b1.w;
    s += __shfl_xor(s, 16, 64);
    s += __shfl_xor(s, 32, 64);
    if (l16 == 0) cn[(size_t)lg * NK + k] = 0.5f * s;
}

// ---------------- fast path: main kernel v5 ----------------
struct Frag { f16x8 h0, h1, l0, l1; };

__device__ __forceinline__ void load_stage(const _Float16* fb, const float* cnl,
                                           int kl, int lane, int s,
                                           Frag& F, float& cv) {
    const _Float16* p = fb + (size_t)s * 2048 + lane * 8;
    F.h0 = *(const f16x8*)(p);
    F.h1 = *(const f16x8*)(p + 512);
    F.l0 = *(const f16x8*)(p + 1024);
    F.l1 = *(const f16x8*)(p + 1536);
    cv = cnl[kl + s * 16];
}

__device__ __forceinline__ void do_stage(const Frag& F, float cv, int s,
                                         const f16x8 (&ah)[2][2], const f16x8 (&al)[2][2],
                                         const f32x4& Z,
                                         float (&minv)[2][4], int (&mini)[2][4]) {
    f32x4 a0, a1;
    a0 = __builtin_amdgcn_mfma_f32_16x16x32_f16(ah[0][0], F.h0, Z, 0, 0, 0);
    a1 = __builtin_amdgcn_mfma_f32_16x16x32_f16(ah[1][0], F.h0, Z, 0, 0, 0);
    a0 = __builtin_amdgcn_mfma_f32_16x16x32_f16(ah[0][1], F.h1, a0, 0, 0, 0);
    a1 = __builtin_amdgcn_mfma_f32_16x16x32_f16(ah[1][1], F.h1, a1, 0, 0, 0);
    a0 = __builtin_amdgcn_mfma_f32_16x16x32_f16(ah[0][0], F.l0, a0, 0, 0, 0);
    a1 = __builtin_amdgcn_mfma_f32_16x16x32_f16(ah[1][0], F.l0, a1, 0, 0, 0);
    a0 = __builtin_amdgcn_mfma_f32_16x16x32_f16(ah[0][1], F.l1, a0, 0, 0, 0);
    a1 = __builtin_amdgcn_mfma_f32_16x16x32_f16(ah[1][1], F.l1, a1, 0, 0, 0);
    a0 = __builtin_amdgcn_mfma_f32_16x16x32_f16(al[0][0], F.h0, a0, 0, 0, 0);
    a1 = __builtin_amdgcn_mfma_f32_16x16x32_f16(al[1][0], F.h0, a1, 0, 0, 0);
    a0 = __builtin_amdgcn_mfma_f32_16x16x32_f16(al[0][1], F.h1, a0, 0, 0, 0);
    a1 = __builtin_amdgcn_mfma_f32_16x16x32_f16(al[1][1], F.h1, a1, 0, 0, 0);
#pragma unroll
    for (int j = 0; j < 4; ++j) {
        float s0 = a0[j] + cv;
        bool lt0 = s0 < minv[0][j];
        minv[0][j] = lt0 ? s0 : minv[0][j];
        mini[0][j] = lt0 ? s : mini[0][j];      // s is compile-time const
        float s1 = a1[j] + cv;
        bool lt1 = s1 < minv[1][j];
        minv[1][j] = lt1 ? s1 : minv[1][j];
        mini[1][j] = lt1 ? s : mini[1][j];
    }
}

// 512 blocks x 512 threads. Block owns 64 rows; wave = (row-half, k-quarter):
// 32 rows x 512 cw. No barriers in the k-loop.
// launch_bounds min-waves/EU = 2: round-4's (512,4) capped VGPR at 64 and
// spilled ~1 GB to scratch; (·,2) matches round-3's proven no-spill regime
// while actual usage (~110-130) still yields 4 waves/SIMD.
__global__ __launch_bounds__(512, 2) void cq_main5_kernel(
    const float* __restrict__ x, const float* __restrict__ cb,
    const _Float16* __restrict__ wfrag, const float* __restrict__ cn,
    float* __restrict__ out)
{
    __shared__ float r_lds[64][RS];
    __shared__ float mv_lds[4][64];
    __shared__ int   mi_lds[4][64];
    __shared__ int   ks_lds[64];

    const int tid = threadIdx.x;
    const int blk = blockIdx.x;       // 512 = 8b * 4g * 16nt
    const int nt  = blk & 15;
    const int g   = (blk >> 4) & 3;
    const int b   = blk >> 6;
    const int n0  = nt * 64;

    const float* xb = x + ((size_t)(b * NC + g * ND)) * NHW + n0;
#pragma unroll
    for (int dd = 0; dd < 2; ++dd) {
        int d = (tid >> 4) + dd * 32;
        int n = (tid & 15) * 4;
        float4 xv = *(const float4*)(&xb[(size_t)d * NHW + n]);
        r_lds[n + 0][d] = xv.x; r_lds[n + 1][d] = xv.y;
        r_lds[n + 2][d] = xv.z; r_lds[n + 3][d] = xv.w;
    }
    __syncthreads();

    const int lane = tid & 63;
    const int w    = tid >> 6;        // 8 waves
    const int rh   = w & 1;           // row half
    const int kq   = w >> 1;          // k quarter
    const int l4   = lane & 15;
    const int l16  = lane >> 4;
    const int kbase = kq * 512;

    const f32x4 Z = {0.f, 0.f, 0.f, 0.f};

    for (int l = 0; l < NL; ++l) {
        const float* cbl_g = cb + (size_t)(l * NG + g) * NK * ND;
        const float* cnl   = cn + (size_t)(l * NG + g) * NK;
        const _Float16* fb = wfrag + ((size_t)(l * NG + g) * 128 + kq * 32) * 2048;
        const int kl = kbase + l4;

        // negated hi/lo A fragments: rows rh*32+ns*16+l4, d = c*32+l16*8+j
        f16x8 ah[2][2], al[2][2];
#pragma unroll
        for (int ns = 0; ns < 2; ++ns) {
#pragma unroll
            for (int c = 0; c < 2; ++c) {
                const float* rp = &r_lds[rh * 32 + ns * 16 + l4][c * 32 + l16 * 8];
                float4 v0 = *(const float4*)(rp);
                float4 v1 = *(const float4*)(rp + 4);
                _Float16 h, lo; f16x8 hv, lv;
                fsplit(-v0.x,h,lo); hv[0]=h; lv[0]=lo;
                fsplit(-v0.y,h,lo); hv[1]=h; lv[1]=lo;
                fsplit(-v0.z,h,lo); hv[2]=h; lv[2]=lo;
                fsplit(-v0.w,h,lo); hv[3]=h; lv[3]=lo;
                fsplit(-v1.x,h,lo); hv[4]=h; lv[4]=lo;
                fsplit(-v1.y,h,lo); hv[5]=h; lv[5]=lo;
                fsplit(-v1.z,h,lo); hv[6]=h; lv[6]=lo;
                fsplit(-v1.w,h,lo); hv[7]=h; lv[7]=lo;
                ah[ns][c] = hv; al[ns][c] = lv;
            }
        }

        float minv[2][4];
        int   mini[2][4];
#pragma unroll
        for (int i = 0; i < 2; ++i)
#pragma unroll
            for (int j = 0; j < 4; ++j) { minv[i][j] = 3.4e38f; mini[i][j] = 0; }

        // register double-buffer, 2 stages/iter, no copies
        Frag X, Y; float cvX, cvY;
        load_stage(fb, cnl, kl, lane, 0, X, cvX);
#pragma unroll
        for (int i = 0; i < 16; ++i) {
            load_stage(fb, cnl, kl, lane, 2 * i + 1, Y, cvY);
            do_stage(X, cvX, 2 * i, ah, al, Z, minv, mini);
            if (i < 15) load_stage(fb, cnl, kl, lane, 2 * i + 2, X, cvX);
            do_stage(Y, cvY, 2 * i + 1, ah, al, Z, minv, mini);
        }

        // reconstruct k, reduce over the 16 k-lanes (ties -> lower k)
        int kk[2][4];
#pragma unroll
        for (int ns = 0; ns < 2; ++ns)
#pragma unroll
            for (int j = 0; j < 4; ++j)
                kk[ns][j] = kbase + mini[ns][j] * 16 + l4;
#pragma unroll
        for (int m = 1; m < 16; m <<= 1) {
#pragma unroll
            for (int ns = 0; ns < 2; ++ns)
#pragma unroll
                for (int j = 0; j < 4; ++j) {
                    float ov = __shfl_xor(minv[ns][j], m, 64);
                    int   oi = __shfl_xor(kk[ns][j], m, 64);
                    if (ov < minv[ns][j] || (ov == minv[ns][j] && oi < kk[ns][j])) {
                        minv[ns][j] = ov; kk[ns][j] = oi;
                    }
                }
        }
        if (l4 == 0) {
#pragma unroll
            for (int ns = 0; ns < 2; ++ns)
#pragma unroll
                for (int j = 0; j < 4; ++j) {
                    int row = rh * 32 + ns * 16 + l16 * 4 + j;  // C/D row map
                    mv_lds[kq][row] = minv[ns][j];
                    mi_lds[kq][row] = kk[ns][j];
                }
        }
        __syncthreads();
        if (tid < 64) {   // combine 4 quarters ascending (tie -> lower k)
            float bv = mv_lds[0][tid]; int bi = mi_lds[0][tid];
#pragma unroll
            for (int q = 1; q < 4; ++q) {
                float v = mv_lds[q][tid];
                if (v < bv) { bv = v; bi = mi_lds[q][tid]; }
            }
            ks_lds[tid] = bi;
        }
        __syncthreads();

        // r -= cb[k*]  (exact fp32, rows L2-hot)
        {
            int row = tid >> 3, dc = (tid & 7) * 8;
            int kw = ks_lds[row];
            const float* qp = cbl_g + (size_t)kw * ND + dc;
#pragma unroll
            for (int i = 0; i < 2; ++i) {
                float4 q  = *(const float4*)(qp + i * 4);
                float* rp = &r_lds[row][dc + i * 4];
                float4 rv = *(float4*)rp;
                rv.x -= q.x; rv.y -= q.y; rv.z -= q.z; rv.w -= q.w;
                *(float4*)rp = rv;
            }
        }
        __syncthreads();
    }

    // out = x - r_final
    float* ob = out + ((size_t)(b * NC + g * ND)) * NHW + n0;
#pragma unroll
    for (int dd = 0; dd < 2; ++dd) {
        int d = (tid >> 4) + dd * 32;
        int n = (tid & 15) * 4;
        float4 xv = *(const float4*)(&xb[(size_t)d * NHW + n]);
        float4 ov;
        ov.x = xv.x - r_lds[n + 0][d];
        ov.y = xv.y - r_lds[n + 1][d];
        ov.z = xv.z - r_lds[n + 2][d];
        ov.w = xv.w - r_lds[n + 3][d];
        *(float4*)(&ob[(size_t)d * NHW + n]) = ov;
    }
}

// ---------------- fallback path (round-2 kernels, 128 KB ws) ----------------
__global__ void cq_cnorm_kernel(const float* __restrict__ cb, float* __restrict__ cn) {
    int idx = blockIdx.x * 256 + threadIdx.x;
    const float4* p = reinterpret_cast<const float4*>(cb + (size_t)idx * ND);
    float s = 0.f;
#pragma unroll
    for (int i = 0; i < ND / 4; ++i) {
        float4 v = p[i];
        s += v.x * v.x + v.y * v.y + v.z * v.z + v.w * v.w;
    }
    cn[idx] = 0.5f * s;
}

__global__ __launch_bounds__(256, 1) void cq_main_kernel(
    const float* __restrict__ x, const float* __restrict__ cb,
    const float* __restrict__ cn, float* __restrict__ out)
{
    __shared__ float    r_lds[128][RS];
    __shared__ _Float16 cbh_lds[2][128][CS];
    __shared__ _Float16 cbl_lds[2][128][CS];
    __shared__ float    mv_lds[2][128];
    __shared__ int      mi_lds[2][128];
    __shared__ int      ks_lds[128];

    const int tid = threadIdx.x;
    const int blk = blockIdx.x;
    const int nt  = blk & 7;
    const int bg  = blk >> 3;
    const int g   = bg & 3;
    const int b   = bg >> 2;
    const int n0  = nt * 128;

    const float* xb = x + ((size_t)(b * NC + g * ND)) * NHW + n0;
#pragma unroll
    for (int dd = 0; dd < 8; ++dd) {
        int d = (tid >> 5) + dd * 8;
        int n = (tid & 31) * 4;
        float4 xv = *reinterpret_cast<const float4*>(&xb[(size_t)d * NHW + n]);
        r_lds[n + 0][d] = xv.x; r_lds[n + 1][d] = xv.y;
        r_lds[n + 2][d] = xv.z; r_lds[n + 3][d] = xv.w;
    }

    const int lane = tid & 63;
    const int wid  = tid >> 6;
    const int rg   = wid & 1;
    const int kh   = wid >> 1;
    const int l4   = lane & 15;
    const int l16  = lane >> 4;

    __syncthreads();

    for (int l = 0; l < NL; ++l) {
        const float* cbl_g = cb + (size_t)(l * NG + g) * NK * ND;
        const float* cnl   = cn + (size_t)(l * NG + g) * NK;

        f16x8 ah[4][2], al[4][2];
#pragma unroll
        for (int ns = 0; ns < 4; ++ns) {
#pragma unroll
            for (int c = 0; c < 2; ++c) {
                const float* rp = &r_lds[rg * 64 + ns * 16 + l4][c * 32 + l16 * 8];
                float4 v0 = *reinterpret_cast<const float4*>(rp);
                float4 v1 = *reinterpret_cast<const float4*>(rp + 4);
                _Float16 h, lo; f16x8 hv, lv;
                fsplit(-v0.x, h, lo); hv[0] = h; lv[0] = lo;
                fsplit(-v0.y, h, lo); hv[1] = h; lv[1] = lo;
                fsplit(-v0.z, h, lo); hv[2] = h; lv[2] = lo;
                fsplit(-v0.w, h, lo); hv[3] = h; lv[3] = lo;
                fsplit(-v1.x, h, lo); hv[4] = h; lv[4] = lo;
                fsplit(-v1.y, h, lo); hv[5] = h; lv[5] = lo;
                fsplit(-v1.z, h, lo); hv[6] = h; lv[6] = lo;
                fsplit(-v1.w, h, lo); hv[7] = h; lv[7] = lo;
                ah[ns][c] = hv; al[ns][c] = lv;
            }
        }

        float minv[4][4];
        int   mini[4][4];
#pragma unroll
        for (int i = 0; i < 4; ++i)
#pragma unroll
            for (int j = 0; j < 4; ++j) { minv[i][j] = 3.4e38f; mini[i][j] = 0; }

        float4 sreg[8];
#pragma unroll
        for (int p = 0; p < 8; ++p) {
            int kk = p * 16 + (tid >> 4);
            int kg = (kk < 64) ? kk : (1024 - 64 + kk);
            sreg[p] = *reinterpret_cast<const float4*>(&cbl_g[(size_t)kg * ND + (tid & 15) * 4]);
        }
#pragma unroll
        for (int p = 0; p < 8; ++p) {
            int kk = p * 16 + (tid >> 4);
            float4 v = sreg[p];
            _Float16 h, lo; f16x4 hv, lv;
            fsplit(v.x, h, lo); hv[0] = h; lv[0] = lo;
            fsplit(v.y, h, lo); hv[1] = h; lv[1] = lo;
            fsplit(v.z, h, lo); hv[2] = h; lv[2] = lo;
            fsplit(v.w, h, lo); hv[3] = h; lv[3] = lo;
            *reinterpret_cast<f16x4*>(&cbh_lds[0][kk][(tid & 15) * 4]) = hv;
            *reinterpret_cast<f16x4*>(&cbl_lds[0][kk][(tid & 15) * 4]) = lv;
        }

        for (int s = 0; s < 16; ++s) {
            __syncthreads();

            if (s < 15) {
#pragma unroll
                for (int p = 0; p < 8; ++p) {
                    int kk = p * 16 + (tid >> 4);
                    int kg = (kk < 64) ? ((s + 1) * 64 + kk) : (1024 + (s + 1) * 64 + (kk - 64));
                    sreg[p] = *reinterpret_cast<const float4*>(&cbl_g[(size_t)kg * ND + (tid & 15) * 4]);
                }
            }

            const int buf = s & 1;
            for (int ks = 0; ks < 4; ++ks) {
                int lrow = kh * 64 + ks * 16 + l4;
                int kabs = kh * 1024 + s * 64 + ks * 16 + l4;
                f16x8 bh0 = *reinterpret_cast<const f16x8*>(&cbh_lds[buf][lrow][l16 * 8]);
                f16x8 bh1 = *reinterpret_cast<const f16x8*>(&cbh_lds[buf][lrow][32 + l16 * 8]);
                f16x8 bl0 = *reinterpret_cast<const f16x8*>(&cbl_lds[buf][lrow][l16 * 8]);
                f16x8 bl1 = *reinterpret_cast<const f16x8*>(&cbl_lds[buf][lrow][32 + l16 * 8]);
                float cnv = cnl[kabs];
                f32x4 acc[4];
#pragma unroll
                for (int ns = 0; ns < 4; ++ns) acc[ns] = (f32x4){cnv, cnv, cnv, cnv};
#pragma unroll
                for (int ns = 0; ns < 4; ++ns) {
                    acc[ns] = __builtin_amdgcn_mfma_f32_16x16x32_f16(ah[ns][0], bh0, acc[ns], 0, 0, 0);
                    acc[ns] = __builtin_amdgcn_mfma_f32_16x16x32_f16(ah[ns][1], bh1, acc[ns], 0, 0, 0);
                    acc[ns] = __builtin_amdgcn_mfma_f32_16x16x32_f16(ah[ns][0], bl0, acc[ns], 0, 0, 0);
                    acc[ns] = __builtin_amdgcn_mfma_f32_16x16x32_f16(ah[ns][1], bl1, acc[ns], 0, 0, 0);
                    acc[ns] = __builtin_amdgcn_mfma_f32_16x16x32_f16(al[ns][0], bh0, acc[ns], 0, 0, 0);
                    acc[ns] = __builtin_amdgcn_mfma_f32_16x16x32_f16(al[ns][1], bh1, acc[ns], 0, 0, 0);
                }
#pragma unroll
                for (int ns = 0; ns < 4; ++ns)
#pragma unroll
                    for (int j = 0; j < 4; ++j) {
                        float sc = acc[ns][j];
                        bool lt = sc < minv[ns][j];
                        minv[ns][j] = lt ? sc : minv[ns][j];
                        mini[ns][j] = lt ? kabs : mini[ns][j];
                    }
            }

            if (s < 15) {
                const int nbuf = (s + 1) & 1;
#pragma unroll
                for (int p = 0; p < 8; ++p) {
                    int kk = p * 16 + (tid >> 4);
                    float4 v = sreg[p];
                    _Float16 h, lo; f16x4 hv, lv;
                    fsplit(v.x, h, lo); hv[0] = h; lv[0] = lo;
                    fsplit(v.y, h, lo); hv[1] = h; lv[1] = lo;
                    fsplit(v.z, h, lo); hv[2] = h; lv[2] = lo;
                    fsplit(v.w, h, lo); hv[3] = h; lv[3] = lo;
                    *reinterpret_cast<f16x4*>(&cbh_lds[nbuf][kk][(tid & 15) * 4]) = hv;
                    *reinterpret_cast<f16x4*>(&cbl_lds[nbuf][kk][(tid & 15) * 4]) = lv;
                }
            }
        }

#pragma unroll
        for (int m = 1; m < 16; m <<= 1) {
#pragma unroll
            for (int ns = 0; ns < 4; ++ns)
#pragma unroll
                for (int j = 0; j < 4; ++j) {
                    float ov = __shfl_xor(minv[ns][j], m, 64);
                    int   oi = __shfl_xor(mini[ns][j], m, 64);
                    if (ov < minv[ns][j] || (ov == minv[ns][j] && oi < mini[ns][j])) {
                        minv[ns][j] = ov; mini[ns][j] = oi;
                    }
                }
        }
        if (l4 == 0) {
#pragma unroll
            for (int ns = 0; ns < 4; ++ns)
#pragma unroll
                for (int j = 0; j < 4; ++j) {
                    int row = rg * 64 + ns * 16 + l16 * 4 + j;
                    mv_lds[kh][row] = minv[ns][j];
                    mi_lds[kh][row] = mini[ns][j];
                }
        }
        __syncthreads();
        if (tid < 128) {
            float v0 = mv_lds[0][tid], v1 = mv_lds[1][tid];
            ks_lds[tid] = (v1 < v0) ? mi_lds[1][tid] : mi_lds[0][tid];
        }
        __syncthreads();

        {
            int n  = tid >> 1;
            int db = (tid & 1) * 32;
            int kw = ks_lds[n];
            const float* qp = &cbl_g[(size_t)kw * ND + db];
#pragma unroll
            for (int i = 0; i < 8; ++i) {
                float4 q  = *reinterpret_cast<const float4*>(&qp[i * 4]);
                float* rp = &r_lds[n][db + i * 4];
                float4 rv = *reinterpret_cast<float4*>(rp);
                rv.x -= q.x; rv.y -= q.y; rv.z -= q.z; rv.w -= q.w;
                *reinterpret_cast<float4*>(rp) = rv;
            }
        }
        __syncthreads();
    }

    float* ob = out + ((size_t)(b * NC + g * ND)) * NHW + n0;
#pragma unroll
    for (int dd = 0; dd < 8; ++dd) {
        int d = (tid >> 5) + dd * 8;
        int n = (tid & 31) * 4;
        float4 xv = *reinterpret_cast<const float4*>(&xb[(size_t)d * NHW + n]);
        float4 ov;
        ov.x = xv.x - r_lds[n + 0][d];
        ov.y = xv.y - r_lds[n + 1][d];
        ov.z = xv.z - r_lds[n + 2][d];
        ov.w = xv.w - r_lds[n + 3][d];
        *reinterpret_cast<float4*>(&ob[(size_t)d * NHW + n]) = ov;
    }
}

extern "C" void kernel_launch(void* const* d_in, const int* in_sizes, int n_in,
                              void* d_out, int out_size, void* d_ws, size_t ws_size,
                              hipStream_t stream) {
    const float* x  = (const float*)d_in[0];   // [B, C, H, W]
    const float* cb = (const float*)d_in[1];   // [L, G, K, D]
    float* out = (float*)d_out;

    const size_t FRAG_BYTES = (size_t)NL * NG * NK * ND * 2 * 2;  // 8 MiB
    const size_t NEED = FRAG_BYTES + (size_t)NL * NG * NK * 4;    // + cn

    if (ws_size >= NEED) {
        _Float16* wfrag = (_Float16*)d_ws;
        float* cn = (float*)((char*)d_ws + FRAG_BYTES);
        cq_prep_kernel<<<512, 256, 0, stream>>>(cb, wfrag, cn);
        cq_main5_kernel<<<NB * NG * (NHW / 64), 512, 0, stream>>>(x, cb, wfrag, cn, out);
    } else {
        float* cn = (float*)d_ws;
        cq_cnorm_kernel<<<(NL * NG * NK) / 256, 256, 0, stream>>>(cb, cn);
        cq_main_kernel<<<NB * NG * (NHW / 128), 256, 0, stream>>>(x, cb, cn, out);
    }
}

// Round 6
// 180.877 us; speedup vs baseline: 3.9080x; 1.3387x over previous
//
#include <hip/hip_runtime.h>

#define NB 8
#define NC 256
#define NHW 1024   // H*W
#define NL 4
#define NG 4
#define NK 2048
#define ND 64      // C/G

#define RS 68      // r_lds row stride (floats)
#define CS 72      // (fallback kernel) codebook LDS row stride (halfs)

typedef __attribute__((ext_vector_type(8))) _Float16 f16x8;
typedef __attribute__((ext_vector_type(4))) _Float16 f16x4;
typedef __attribute__((ext_vector_type(4))) float    f32x4;

// fp16 hi/lo split: v = h + l + O(2^-24 v). Products h*h etc are exact in fp32.
__device__ __forceinline__ void fsplit(float v, _Float16& h, _Float16& l) {
    _Float16 hh = (_Float16)v;
    h = hh;
    l = (_Float16)(v - (float)hh);
}

// ---------------- fast path: prep kernel ----------------
// Per 16-codeword tile: 4 fragments (hiC0, hiC1, loC0, loC1), each 64 lanes x
// 8 halfs, lane-linear (one dwordx4 per lane in the main kernel). Fused cn.
__global__ void cq_prep_kernel(const float* __restrict__ cb,
                               _Float16* __restrict__ wfrag,
                               float* __restrict__ cn) {
    int wv   = (blockIdx.x * 256 + threadIdx.x) >> 6;  // tile id 0..2047
    int lane = threadIdx.x & 63;
    int l4 = lane & 15, l16 = lane >> 4;
    int lg = wv >> 7, kt = wv & 127;
    int k  = kt * 16 + l4;
    const float* src = cb + ((size_t)lg * NK + k) * ND;

    float4 a0 = *(const float4*)(src + l16 * 8);
    float4 a1 = *(const float4*)(src + l16 * 8 + 4);
    float4 b0 = *(const float4*)(src + 32 + l16 * 8);
    float4 b1 = *(const float4*)(src + 32 + l16 * 8 + 4);

    f16x8 h0, lo0, h1, lo1;
    _Float16 h, lo;
    fsplit(a0.x,h,lo); h0[0]=h; lo0[0]=lo;  fsplit(a0.y,h,lo); h0[1]=h; lo0[1]=lo;
    fsplit(a0.z,h,lo); h0[2]=h; lo0[2]=lo;  fsplit(a0.w,h,lo); h0[3]=h; lo0[3]=lo;
    fsplit(a1.x,h,lo); h0[4]=h; lo0[4]=lo;  fsplit(a1.y,h,lo); h0[5]=h; lo0[5]=lo;
    fsplit(a1.z,h,lo); h0[6]=h; lo0[6]=lo;  fsplit(a1.w,h,lo); h0[7]=h; lo0[7]=lo;
    fsplit(b0.x,h,lo); h1[0]=h; lo1[0]=lo;  fsplit(b0.y,h,lo); h1[1]=h; lo1[1]=lo;
    fsplit(b0.z,h,lo); h1[2]=h; lo1[2]=lo;  fsplit(b0.w,h,lo); h1[3]=h; lo1[3]=lo;
    fsplit(b1.x,h,lo); h1[4]=h; lo1[4]=lo;  fsplit(b1.y,h,lo); h1[5]=h; lo1[5]=lo;
    fsplit(b1.z,h,lo); h1[6]=h; lo1[6]=lo;  fsplit(b1.w,h,lo); h1[7]=h; lo1[7]=lo;

    _Float16* outp = wfrag + (size_t)wv * 2048;   // tile = 4096 B
    *(f16x8*)(outp +    0 + lane * 8) = h0;
    *(f16x8*)(outp +  512 + lane * 8) = h1;
    *(f16x8*)(outp + 1024 + lane * 8) = lo0;
    *(f16x8*)(outp + 1536 + lane * 8) = lo1;

    float s = a0.x*a0.x + a0.y*a0.y + a0.z*a0.z + a0.w*a0.w
            + a1.x*a1.x + a1.y*a1.y + a1.z*a1.z + a1.w*a1.w
            + b0.x*b0.x + b0.y*b0.y + b0.z*b0.z + b0.w*b0.w
            + b1.x*b1.x + b1.y*b1.y + b1.z*b1.z + b1.w*b1.w;
    s += __shfl_xor(s, 16, 64);
    s += __shfl_xor(s, 32, 64);
    if (l16 == 0) cn[(size_t)lg * NK + k] = 0.5f * s;
}

// ---------------- fast path: main kernel v6 ----------------
// 256-thread blocks only (512-thread blocks spilled in rounds 4 & 5).
struct Frag { f16x8 h0, h1, l0, l1; };

__device__ __forceinline__ void load_stage(const _Float16* fb, const float* cnl,
                                           int kl, int lane, int s,
                                           Frag& F, float& cv) {
    const _Float16* p = fb + (size_t)s * 2048 + lane * 8;
    F.h0 = *(const f16x8*)(p);
    F.h1 = *(const f16x8*)(p + 512);
    F.l0 = *(const f16x8*)(p + 1024);
    F.l1 = *(const f16x8*)(p + 1536);
    cv = cnl[kl + s * 16];
}

// score = cv - r.c built from zero-C MFMA chains; argmin stores stage id s.
__device__ __forceinline__ void do_stage(const Frag& F, float cv, int s,
                                         const f16x8 (&ah)[2][2], const f16x8 (&al)[2][2],
                                         const f32x4& Z,
                                         float (&minv)[2][4], int (&mini)[2][4]) {
    f32x4 a0, a1;
    a0 = __builtin_amdgcn_mfma_f32_16x16x32_f16(ah[0][0], F.h0, Z, 0, 0, 0);
    a1 = __builtin_amdgcn_mfma_f32_16x16x32_f16(ah[1][0], F.h0, Z, 0, 0, 0);
    a0 = __builtin_amdgcn_mfma_f32_16x16x32_f16(ah[0][1], F.h1, a0, 0, 0, 0);
    a1 = __builtin_amdgcn_mfma_f32_16x16x32_f16(ah[1][1], F.h1, a1, 0, 0, 0);
    a0 = __builtin_amdgcn_mfma_f32_16x16x32_f16(ah[0][0], F.l0, a0, 0, 0, 0);
    a1 = __builtin_amdgcn_mfma_f32_16x16x32_f16(ah[1][0], F.l0, a1, 0, 0, 0);
    a0 = __builtin_amdgcn_mfma_f32_16x16x32_f16(ah[0][1], F.l1, a0, 0, 0, 0);
    a1 = __builtin_amdgcn_mfma_f32_16x16x32_f16(ah[1][1], F.l1, a1, 0, 0, 0);
    a0 = __builtin_amdgcn_mfma_f32_16x16x32_f16(al[0][0], F.h0, a0, 0, 0, 0);
    a1 = __builtin_amdgcn_mfma_f32_16x16x32_f16(al[1][0], F.h0, a1, 0, 0, 0);
    a0 = __builtin_amdgcn_mfma_f32_16x16x32_f16(al[0][1], F.h1, a0, 0, 0, 0);
    a1 = __builtin_amdgcn_mfma_f32_16x16x32_f16(al[1][1], F.h1, a1, 0, 0, 0);
#pragma unroll
    for (int j = 0; j < 4; ++j) {
        float s0 = a0[j] + cv;
        bool lt0 = s0 < minv[0][j];
        minv[0][j] = lt0 ? s0 : minv[0][j];
        mini[0][j] = lt0 ? s : mini[0][j];
        float s1 = a1[j] + cv;
        bool lt1 = s1 < minv[1][j];
        minv[1][j] = lt1 ? s1 : minv[1][j];
        mini[1][j] = lt1 ? s : mini[1][j];
    }
}

// 1024 blocks x 256 threads (4 blocks/CU -> 4 waves/SIMD). Block owns 32 rows;
// each wave owns a k-quarter (512 cw). No barriers in the k-loop.
// XCD-chunked swizzle: same-XCD blocks share (b,g) codebook-fragment L2 lines.
__global__ __launch_bounds__(256, 2) void cq_main6_kernel(
    const float* __restrict__ x, const float* __restrict__ cb,
    const _Float16* __restrict__ wfrag, const float* __restrict__ cn,
    float* __restrict__ out)
{
    __shared__ float r_lds[32][RS];
    __shared__ float mv_lds[4][32];
    __shared__ int   mi_lds[4][32];
    __shared__ int   ks_lds[32];

    const int tid = threadIdx.x;
    // bijective XCD swizzle (1024 = 8 XCD * 128 chunks)
    const int blk = (blockIdx.x & 7) * 128 + (blockIdx.x >> 3);
    const int nt  = blk & 31;          // 32 n-tiles of 32 rows
    const int g   = (blk >> 5) & 3;
    const int b   = blk >> 7;
    const int n0  = nt * 32;

    const float* xb = x + ((size_t)(b * NC + g * ND)) * NHW + n0;
    // 32 rows x 64 d : d = (tid>>3)+dd*32, n = (tid&7)*4
#pragma unroll
    for (int dd = 0; dd < 2; ++dd) {
        int d = (tid >> 3) + dd * 32;
        int n = (tid & 7) * 4;
        float4 xv = *(const float4*)(&xb[(size_t)d * NHW + n]);
        r_lds[n + 0][d] = xv.x; r_lds[n + 1][d] = xv.y;
        r_lds[n + 2][d] = xv.z; r_lds[n + 3][d] = xv.w;
    }
    __syncthreads();

    const int lane = tid & 63;
    const int kq   = tid >> 6;        // k-quarter (4 waves)
    const int l4   = lane & 15;
    const int l16  = lane >> 4;
    const int kbase = kq * 512;

    const f32x4 Z = {0.f, 0.f, 0.f, 0.f};

    for (int l = 0; l < NL; ++l) {
        const float* cbl_g = cb + (size_t)(l * NG + g) * NK * ND;
        const float* cnl   = cn + (size_t)(l * NG + g) * NK;
        const _Float16* fb = wfrag + ((size_t)(l * NG + g) * 128 + kq * 32) * 2048;
        const int kl = kbase + l4;

        // negated hi/lo A fragments: rows ns*16+l4, d = c*32+l16*8+j
        f16x8 ah[2][2], al[2][2];
#pragma unroll
        for (int ns = 0; ns < 2; ++ns) {
#pragma unroll
            for (int c = 0; c < 2; ++c) {
                const float* rp = &r_lds[ns * 16 + l4][c * 32 + l16 * 8];
                float4 v0 = *(const float4*)(rp);
                float4 v1 = *(const float4*)(rp + 4);
                _Float16 h, lo; f16x8 hv, lv;
                fsplit(-v0.x,h,lo); hv[0]=h; lv[0]=lo;
                fsplit(-v0.y,h,lo); hv[1]=h; lv[1]=lo;
                fsplit(-v0.z,h,lo); hv[2]=h; lv[2]=lo;
                fsplit(-v0.w,h,lo); hv[3]=h; lv[3]=lo;
                fsplit(-v1.x,h,lo); hv[4]=h; lv[4]=lo;
                fsplit(-v1.y,h,lo); hv[5]=h; lv[5]=lo;
                fsplit(-v1.z,h,lo); hv[6]=h; lv[6]=lo;
                fsplit(-v1.w,h,lo); hv[7]=h; lv[7]=lo;
                ah[ns][c] = hv; al[ns][c] = lv;
            }
        }

        float minv[2][4];
        int   mini[2][4];
#pragma unroll
        for (int i = 0; i < 2; ++i)
#pragma unroll
            for (int j = 0; j < 4; ++j) { minv[i][j] = 3.4e38f; mini[i][j] = 0; }

        // register double-buffer, 2 stages/iter, no copies; partial unroll
        // (full unroll is a spill suspect - rounds 4/5)
        Frag X, Y; float cvX, cvY;
        load_stage(fb, cnl, kl, lane, 0, X, cvX);
#pragma unroll 2
        for (int i = 0; i < 16; ++i) {
            load_stage(fb, cnl, kl, lane, 2 * i + 1, Y, cvY);
            do_stage(X, cvX, 2 * i, ah, al, Z, minv, mini);
            if (i < 15) load_stage(fb, cnl, kl, lane, 2 * i + 2, X, cvX);
            do_stage(Y, cvY, 2 * i + 1, ah, al, Z, minv, mini);
        }

        // reconstruct k, reduce over the 16 k-lanes (ties -> lower k)
        int kk[2][4];
#pragma unroll
        for (int ns = 0; ns < 2; ++ns)
#pragma unroll
            for (int j = 0; j < 4; ++j)
                kk[ns][j] = kl + mini[ns][j] * 16;
#pragma unroll
        for (int m = 1; m < 16; m <<= 1) {
#pragma unroll
            for (int ns = 0; ns < 2; ++ns)
#pragma unroll
                for (int j = 0; j < 4; ++j) {
                    float ov = __shfl_xor(minv[ns][j], m, 64);
                    int   oi = __shfl_xor(kk[ns][j], m, 64);
                    if (ov < minv[ns][j] || (ov == minv[ns][j] && oi < kk[ns][j])) {
                        minv[ns][j] = ov; kk[ns][j] = oi;
                    }
                }
        }
        if (l4 == 0) {
#pragma unroll
            for (int ns = 0; ns < 2; ++ns)
#pragma unroll
                for (int j = 0; j < 4; ++j) {
                    int row = ns * 16 + l16 * 4 + j;   // C/D: row=(lane>>4)*4+reg
                    mv_lds[kq][row] = minv[ns][j];
                    mi_lds[kq][row] = kk[ns][j];
                }
        }
        __syncthreads();
        if (tid < 32) {   // combine 4 quarters ascending (tie -> lower k)
            float bv = mv_lds[0][tid]; int bi = mi_lds[0][tid];
#pragma unroll
            for (int q = 1; q < 4; ++q) {
                float v = mv_lds[q][tid];
                if (v < bv) { bv = v; bi = mi_lds[q][tid]; }
            }
            ks_lds[tid] = bi;
        }
        __syncthreads();

        // r -= cb[k*]  (exact fp32, rows L2-hot)
        {
            int row = tid >> 3, dc = (tid & 7) * 8;
            int kw = ks_lds[row];
            const float* qp = cbl_g + (size_t)kw * ND + dc;
#pragma unroll
            for (int i = 0; i < 2; ++i) {
                float4 q  = *(const float4*)(qp + i * 4);
                float* rp = &r_lds[row][dc + i * 4];
                float4 rv = *(float4*)rp;
                rv.x -= q.x; rv.y -= q.y; rv.z -= q.z; rv.w -= q.w;
                *(float4*)rp = rv;
            }
        }
        __syncthreads();
    }

    // out = x - r_final
    float* ob = out + ((size_t)(b * NC + g * ND)) * NHW + n0;
#pragma unroll
    for (int dd = 0; dd < 2; ++dd) {
        int d = (tid >> 3) + dd * 32;
        int n = (tid & 7) * 4;
        float4 xv = *(const float4*)(&xb[(size_t)d * NHW + n]);
        float4 ov;
        ov.x = xv.x - r_lds[n + 0][d];
        ov.y = xv.y - r_lds[n + 1][d];
        ov.z = xv.z - r_lds[n + 2][d];
        ov.w = xv.w - r_lds[n + 3][d];
        *(float4*)(&ob[(size_t)d * NHW + n]) = ov;
    }
}

// ---------------- fallback path (round-2 kernels, 128 KB ws) ----------------
__global__ void cq_cnorm_kernel(const float* __restrict__ cb, float* __restrict__ cn) {
    int idx = blockIdx.x * 256 + threadIdx.x;
    const float4* p = reinterpret_cast<const float4*>(cb + (size_t)idx * ND);
    float s = 0.f;
#pragma unroll
    for (int i = 0; i < ND / 4; ++i) {
        float4 v = p[i];
        s += v.x * v.x + v.y * v.y + v.z * v.z + v.w * v.w;
    }
    cn[idx] = 0.5f * s;
}

__global__ __launch_bounds__(256, 1) void cq_main_kernel(
    const float* __restrict__ x, const float* __restrict__ cb,
    const float* __restrict__ cn, float* __restrict__ out)
{
    __shared__ float    r_lds[128][RS];
    __shared__ _Float16 cbh_lds[2][128][CS];
    __shared__ _Float16 cbl_lds[2][128][CS];
    __shared__ float    mv_lds[2][128];
    __shared__ int      mi_lds[2][128];
    __shared__ int      ks_lds[128];

    const int tid = threadIdx.x;
    const int blk = blockIdx.x;
    const int nt  = blk & 7;
    const int bg  = blk >> 3;
    const int g   = bg & 3;
    const int b   = bg >> 2;
    const int n0  = nt * 128;

    const float* xb = x + ((size_t)(b * NC + g * ND)) * NHW + n0;
#pragma unroll
    for (int dd = 0; dd < 8; ++dd) {
        int d = (tid >> 5) + dd * 8;
        int n = (tid & 31) * 4;
        float4 xv = *reinterpret_cast<const float4*>(&xb[(size_t)d * NHW + n]);
        r_lds[n + 0][d] = xv.x; r_lds[n + 1][d] = xv.y;
        r_lds[n + 2][d] = xv.z; r_lds[n + 3][d] = xv.w;
    }

    const int lane = tid & 63;
    const int wid  = tid >> 6;
    const int rg   = wid & 1;
    const int kh   = wid >> 1;
    const int l4   = lane & 15;
    const int l16  = lane >> 4;

    __syncthreads();

    for (int l = 0; l < NL; ++l) {
        const float* cbl_g = cb + (size_t)(l * NG + g) * NK * ND;
        const float* cnl   = cn + (size_t)(l * NG + g) * NK;

        f16x8 ah[4][2], al[4][2];
#pragma unroll
        for (int ns = 0; ns < 4; ++ns) {
#pragma unroll
            for (int c = 0; c < 2; ++c) {
                const float* rp = &r_lds[rg * 64 + ns * 16 + l4][c * 32 + l16 * 8];
                float4 v0 = *reinterpret_cast<const float4*>(rp);
                float4 v1 = *reinterpret_cast<const float4*>(rp + 4);
                _Float16 h, lo; f16x8 hv, lv;
                fsplit(-v0.x, h, lo); hv[0] = h; lv[0] = lo;
                fsplit(-v0.y, h, lo); hv[1] = h; lv[1] = lo;
                fsplit(-v0.z, h, lo); hv[2] = h; lv[2] = lo;
                fsplit(-v0.w, h, lo); hv[3] = h; lv[3] = lo;
                fsplit(-v1.x, h, lo); hv[4] = h; lv[4] = lo;
                fsplit(-v1.y, h, lo); hv[5] = h; lv[5] = lo;
                fsplit(-v1.z, h, lo); hv[6] = h; lv[6] = lo;
                fsplit(-v1.w, h, lo); hv[7] = h; lv[7] = lo;
                ah[ns][c] = hv; al[ns][c] = lv;
            }
        }

        float minv[4][4];
        int   mini[4][4];
#pragma unroll
        for (int i = 0; i < 4; ++i)
#pragma unroll
            for (int j = 0; j < 4; ++j) { minv[i][j] = 3.4e38f; mini[i][j] = 0; }

        float4 sreg[8];
#pragma unroll
        for (int p = 0; p < 8; ++p) {
            int kk = p * 16 + (tid >> 4);
            int kg = (kk < 64) ? kk : (1024 - 64 + kk);
            sreg[p] = *reinterpret_cast<const float4*>(&cbl_g[(size_t)kg * ND + (tid & 15) * 4]);
        }
#pragma unroll
        for (int p = 0; p < 8; ++p) {
            int kk = p * 16 + (tid >> 4);
            float4 v = sreg[p];
            _Float16 h, lo; f16x4 hv, lv;
            fsplit(v.x, h, lo); hv[0] = h; lv[0] = lo;
            fsplit(v.y, h, lo); hv[1] = h; lv[1] = lo;
            fsplit(v.z, h, lo); hv[2] = h; lv[2] = lo;
            fsplit(v.w, h, lo); hv[3] = h; lv[3] = lo;
            *reinterpret_cast<f16x4*>(&cbh_lds[0][kk][(tid & 15) * 4]) = hv;
            *reinterpret_cast<f16x4*>(&cbl_lds[0][kk][(tid & 15) * 4]) = lv;
        }

        for (int s = 0; s < 16; ++s) {
            __syncthreads();

            if (s < 15) {
#pragma unroll
                for (int p = 0; p < 8; ++p) {
                    int kk = p * 16 + (tid >> 4);
                    int kg = (kk < 64) ? ((s + 1) * 64 + kk) : (1024 + (s + 1) * 64 + (kk - 64));
                    sreg[p] = *reinterpret_cast<const float4*>(&cbl_g[(size_t)kg * ND + (tid & 15) * 4]);
                }
            }

            const int buf = s & 1;
            for (int ks = 0; ks < 4; ++ks) {
                int lrow = kh * 64 + ks * 16 + l4;
                int kabs = kh * 1024 + s * 64 + ks * 16 + l4;
                f16x8 bh0 = *reinterpret_cast<const f16x8*>(&cbh_lds[buf][lrow][l16 * 8]);
                f16x8 bh1 = *reinterpret_cast<const f16x8*>(&cbh_lds[buf][lrow][32 + l16 * 8]);
                f16x8 bl0 = *reinterpret_cast<const f16x8*>(&cbl_lds[buf][lrow][l16 * 8]);
                f16x8 bl1 = *reinterpret_cast<const f16x8*>(&cbl_lds[buf][lrow][32 + l16 * 8]);
                float cnv = cnl[kabs];
                f32x4 acc[4];
#pragma unroll
                for (int ns = 0; ns < 4; ++ns) acc[ns] = (f32x4){cnv, cnv, cnv, cnv};
#pragma unroll
                for (int ns = 0; ns < 4; ++ns) {
                    acc[ns] = __builtin_amdgcn_mfma_f32_16x16x32_f16(ah[ns][0], bh0, acc[ns], 0, 0, 0);
                    acc[ns] = __builtin_amdgcn_mfma_f32_16x16x32_f16(ah[ns][1], bh1, acc[ns], 0, 0, 0);
                    acc[ns] = __builtin_amdgcn_mfma_f32_16x16x32_f16(ah[ns][0], bl0, acc[ns], 0, 0, 0);
                    acc[ns] = __builtin_amdgcn_mfma_f32_16x16x32_f16(ah[ns][1], bl1, acc[ns], 0, 0, 0);
                    acc[ns] = __builtin_amdgcn_mfma_f32_16x16x32_f16(al[ns][0], bh0, acc[ns], 0, 0, 0);
                    acc[ns] = __builtin_amdgcn_mfma_f32_16x16x32_f16(al[ns][1], bh1, acc[ns], 0, 0, 0);
                }
#pragma unroll
                for (int ns = 0; ns < 4; ++ns)
#pragma unroll
                    for (int j = 0; j < 4; ++j) {
                        float sc = acc[ns][j];
                        bool lt = sc < minv[ns][j];
                        minv[ns][j] = lt ? sc : minv[ns][j];
                        mini[ns][j] = lt ? kabs : mini[ns][j];
                    }
            }

            if (s < 15) {
                const int nbuf = (s + 1) & 1;
#pragma unroll
                for (int p = 0; p < 8; ++p) {
                    int kk = p * 16 + (tid >> 4);
                    float4 v = sreg[p];
                    _Float16 h, lo; f16x4 hv, lv;
                    fsplit(v.x, h, lo); hv[0] = h; lv[0] = lo;
                    fsplit(v.y, h, lo); hv[1] = h; lv[1] = lo;
                    fsplit(v.z, h, lo); hv[2] = h; lv[2] = lo;
                    fsplit(v.w, h, lo); hv[3] = h; lv[3] = lo;
                    *reinterpret_cast<f16x4*>(&cbh_lds[nbuf][kk][(tid & 15) * 4]) = hv;
                    *reinterpret_cast<f16x4*>(&cbl_lds[nbuf][kk][(tid & 15) * 4]) = lv;
                }
            }
        }

#pragma unroll
        for (int m = 1; m < 16; m <<= 1) {
#pragma unroll
            for (int ns = 0; ns < 4; ++ns)
#pragma unroll
                for (int j = 0; j < 4; ++j) {
                    float ov = __shfl_xor(minv[ns][j], m, 64);
                    int   oi = __shfl_xor(mini[ns][j], m, 64);
                    if (ov < minv[ns][j] || (ov == minv[ns][j] && oi < mini[ns][j])) {
                        minv[ns][j] = ov; mini[ns][j] = oi;
                    }
                }
        }
        if (l4 == 0) {
#pragma unroll
            for (int ns = 0; ns < 4; ++ns)
#pragma unroll
                for (int j = 0; j < 4; ++j) {
                    int row = rg * 64 + ns * 16 + l16 * 4 + j;
                    mv_lds[kh][row] = minv[ns][j];
                    mi_lds[kh][row] = mini[ns][j];
                }
        }
        __syncthreads();
        if (tid < 128) {
            float v0 = mv_lds[0][tid], v1 = mv_lds[1][tid];
            ks_lds[tid] = (v1 < v0) ? mi_lds[1][tid] : mi_lds[0][tid];
        }
        __syncthreads();

        {
            int n  = tid >> 1;
            int db = (tid & 1) * 32;
            int kw = ks_lds[n];
            const float* qp = &cbl_g[(size_t)kw * ND + db];
#pragma unroll
            for (int i = 0; i < 8; ++i) {
                float4 q  = *reinterpret_cast<const float4*>(&qp[i * 4]);
                float* rp = &r_lds[n][db + i * 4];
                float4 rv = *reinterpret_cast<float4*>(rp);
                rv.x -= q.x; rv.y -= q.y; rv.z -= q.z; rv.w -= q.w;
                *reinterpret_cast<float4*>(rp) = rv;
            }
        }
        __syncthreads();
    }

    float* ob = out + ((size_t)(b * NC + g * ND)) * NHW + n0;
#pragma unroll
    for (int dd = 0; dd < 8; ++dd) {
        int d = (tid >> 5) + dd * 8;
        int n = (tid & 31) * 4;
        float4 xv = *reinterpret_cast<const float4*>(&xb[(size_t)d * NHW + n]);
        float4 ov;
        ov.x = xv.x - r_lds[n + 0][d];
        ov.y = xv.y - r_lds[n + 1][d];
        ov.z = xv.z - r_lds[n + 2][d];
        ov.w = xv.w - r_lds[n + 3][d];
        *reinterpret_cast<float4*>(&ob[(size_t)d * NHW + n]) = ov;
    }
}

extern "C" void kernel_launch(void* const* d_in, const int* in_sizes, int n_in,
                              void* d_out, int out_size, void* d_ws, size_t ws_size,
                              hipStream_t stream) {
    const float* x  = (const float*)d_in[0];   // [B, C, H, W]
    const float* cb = (const float*)d_in[1];   // [L, G, K, D]
    float* out = (float*)d_out;

    const size_t FRAG_BYTES = (size_t)NL * NG * NK * ND * 2 * 2;  // 8 MiB
    const size_t NEED = FRAG_BYTES + (size_t)NL * NG * NK * 4;    // + cn

    if (ws_size >= NEED) {
        _Float16* wfrag = (_Float16*)d_ws;
        float* cn = (float*)((char*)d_ws + FRAG_BYTES);
        cq_prep_kernel<<<512, 256, 0, stream>>>(cb, wfrag, cn);
        cq_main6_kernel<<<NB * NG * (NHW / 32), 256, 0, stream>>>(x, cb, wfrag, cn, out);
    } else {
        float* cn = (float*)d_ws;
        cq_cnorm_kernel<<<(NL * NG * NK) / 256, 256, 0, stream>>>(cb, cn);
        cq_main_kernel<<<NB * NG * (NHW / 128), 256, 0, stream>>>(x, cb, cn, out);
    }
}

// Round 7
// 122.169 us; speedup vs baseline: 5.7860x; 1.4805x over previous
//
#include <hip/hip_runtime.h>

#define NB 8
#define NC 256
#define NHW 1024   // H*W
#define NL 4
#define NG 4
#define NK 2048
#define ND 64      // C/G

#define RS 68      // r_lds row stride (floats)
#define CS 72      // (fallback kernel) codebook LDS row stride (halfs)

typedef __attribute__((ext_vector_type(8))) _Float16 f16x8;
typedef __attribute__((ext_vector_type(4))) _Float16 f16x4;
typedef __attribute__((ext_vector_type(4))) float    f32x4;

// fp16 hi/lo split: v = h + l + O(2^-24 v). Products h*h etc are exact in fp32.
__device__ __forceinline__ void fsplit(float v, _Float16& h, _Float16& l) {
    _Float16 hh = (_Float16)v;
    h = hh;
    l = (_Float16)(v - (float)hh);
}

// ---------------- fast path: prep kernel ----------------
// Per 16-codeword tile: 4 fragments (hiC0, hiC1, loC0, loC1), each 64 lanes x
// 8 halfs, lane-linear (one dwordx4 per lane in the main kernel). Fused cn.
__global__ void cq_prep_kernel(const float* __restrict__ cb,
                               _Float16* __restrict__ wfrag,
                               float* __restrict__ cn) {
    int wv   = (blockIdx.x * 256 + threadIdx.x) >> 6;  // tile id 0..2047
    int lane = threadIdx.x & 63;
    int l4 = lane & 15, l16 = lane >> 4;
    int lg = wv >> 7, kt = wv & 127;
    int k  = kt * 16 + l4;
    const float* src = cb + ((size_t)lg * NK + k) * ND;

    float4 a0 = *(const float4*)(src + l16 * 8);
    float4 a1 = *(const float4*)(src + l16 * 8 + 4);
    float4 b0 = *(const float4*)(src + 32 + l16 * 8);
    float4 b1 = *(const float4*)(src + 32 + l16 * 8 + 4);

    f16x8 h0, lo0, h1, lo1;
    _Float16 h, lo;
    fsplit(a0.x,h,lo); h0[0]=h; lo0[0]=lo;  fsplit(a0.y,h,lo); h0[1]=h; lo0[1]=lo;
    fsplit(a0.z,h,lo); h0[2]=h; lo0[2]=lo;  fsplit(a0.w,h,lo); h0[3]=h; lo0[3]=lo;
    fsplit(a1.x,h,lo); h0[4]=h; lo0[4]=lo;  fsplit(a1.y,h,lo); h0[5]=h; lo0[5]=lo;
    fsplit(a1.z,h,lo); h0[6]=h; lo0[6]=lo;  fsplit(a1.w,h,lo); h0[7]=h; lo0[7]=lo;
    fsplit(b0.x,h,lo); h1[0]=h; lo1[0]=lo;  fsplit(b0.y,h,lo); h1[1]=h; lo1[1]=lo;
    fsplit(b0.z,h,lo); h1[2]=h; lo1[2]=lo;  fsplit(b0.w,h,lo); h1[3]=h; lo1[3]=lo;
    fsplit(b1.x,h,lo); h1[4]=h; lo1[4]=lo;  fsplit(b1.y,h,lo); h1[5]=h; lo1[5]=lo;
    fsplit(b1.z,h,lo); h1[6]=h; lo1[6]=lo;  fsplit(b1.w,h,lo); h1[7]=h; lo1[7]=lo;

    _Float16* outp = wfrag + (size_t)wv * 2048;   // tile = 4096 B
    *(f16x8*)(outp +    0 + lane * 8) = h0;
    *(f16x8*)(outp +  512 + lane * 8) = h1;
    *(f16x8*)(outp + 1024 + lane * 8) = lo0;
    *(f16x8*)(outp + 1536 + lane * 8) = lo1;

    float s = a0.x*a0.x + a0.y*a0.y + a0.z*a0.z + a0.w*a0.w
            + a1.x*a1.x + a1.y*a1.y + a1.z*a1.z + a1.w*a1.w
            + b0.x*b0.x + b0.y*b0.y + b0.z*b0.z + b0.w*b0.w
            + b1.x*b1.x + b1.y*b1.y + b1.z*b1.z + b1.w*b1.w;
    s += __shfl_xor(s, 16, 64);
    s += __shfl_xor(s, 32, 64);
    if (l16 == 0) cn[(size_t)lg * NK + k] = 0.5f * s;
}

// ---------------- fast path: main kernel v7 ----------------
// v3's proven inner loop (copy-idiom double buffer pipelines the loads;
// VGPR-min scheduling de-pipelined the no-copy version in round 6) at
// 1024-block geometry: 32 rows/block, 4 blocks/CU -> 16 waves/CU.
__global__ __launch_bounds__(256, 2) void cq_main7_kernel(
    const float* __restrict__ x, const float* __restrict__ cb,
    const _Float16* __restrict__ wfrag, const float* __restrict__ cn,
    float* __restrict__ out)
{
    __shared__ float r_lds[32][RS];
    __shared__ float mv_lds[4][32];
    __shared__ int   mi_lds[4][32];
    __shared__ int   ks_lds[32];

    const int tid = threadIdx.x;
    // bijective XCD swizzle (1024 = 8 XCD * 128): same-XCD blocks share g
    // -> share (l,g) fragment panels in that XCD's L2.
    const int blk = (blockIdx.x & 7) * 128 + (blockIdx.x >> 3);
    const int nt  = blk & 31;          // 32 n-tiles of 32 rows
    const int g   = (blk >> 5) & 3;
    const int b   = blk >> 7;
    const int n0  = nt * 32;

    const float* xb = x + ((size_t)(b * NC + g * ND)) * NHW + n0;
#pragma unroll
    for (int dd = 0; dd < 2; ++dd) {
        int d = (tid >> 3) + dd * 32;
        int n = (tid & 7) * 4;
        float4 xv = *(const float4*)(&xb[(size_t)d * NHW + n]);
        r_lds[n + 0][d] = xv.x; r_lds[n + 1][d] = xv.y;
        r_lds[n + 2][d] = xv.z; r_lds[n + 3][d] = xv.w;
    }
    __syncthreads();

    const int lane = tid & 63;
    const int kq   = tid >> 6;        // k-quarter (4 waves)
    const int l4   = lane & 15;
    const int l16  = lane >> 4;
    const int kbase = kq * 512;

    for (int l = 0; l < NL; ++l) {
        const float* cbl_g = cb + (size_t)(l * NG + g) * NK * ND;
        const float* cnl   = cn + (size_t)(l * NG + g) * NK;
        const _Float16* fb = wfrag + ((size_t)(l * NG + g) * 128 + kq * 32) * 2048;

        // negated hi/lo A fragments: rows ns*16+l4, d = c*32+l16*8+j
        f16x8 ah[2][2], al[2][2];
#pragma unroll
        for (int ns = 0; ns < 2; ++ns) {
#pragma unroll
            for (int c = 0; c < 2; ++c) {
                const float* rp = &r_lds[ns * 16 + l4][c * 32 + l16 * 8];
                float4 v0 = *(const float4*)(rp);
                float4 v1 = *(const float4*)(rp + 4);
                _Float16 h, lo; f16x8 hv, lv;
                fsplit(-v0.x,h,lo); hv[0]=h; lv[0]=lo;
                fsplit(-v0.y,h,lo); hv[1]=h; lv[1]=lo;
                fsplit(-v0.z,h,lo); hv[2]=h; lv[2]=lo;
                fsplit(-v0.w,h,lo); hv[3]=h; lv[3]=lo;
                fsplit(-v1.x,h,lo); hv[4]=h; lv[4]=lo;
                fsplit(-v1.y,h,lo); hv[5]=h; lv[5]=lo;
                fsplit(-v1.z,h,lo); hv[6]=h; lv[6]=lo;
                fsplit(-v1.w,h,lo); hv[7]=h; lv[7]=lo;
                ah[ns][c] = hv; al[ns][c] = lv;
            }
        }

        float minv[2][4];
        int   mini[2][4];
#pragma unroll
        for (int i = 0; i < 2; ++i)
#pragma unroll
            for (int j = 0; j < 4; ++j) { minv[i][j] = 3.4e38f; mini[i][j] = 0; }

        // prefetch stage 0 (v3's copy-idiom double buffer: loads land in c*,
        // copies p*=c* consume them BEFORE the next loads re-issue into c* --
        // this forces load-early/use-late and keeps the pipeline)
        f16x8 c0, c1, c2, c3; float cv;
        {
            const _Float16* p = fb + lane * 8;
            c0 = *(const f16x8*)(p);
            c1 = *(const f16x8*)(p + 512);
            c2 = *(const f16x8*)(p + 1024);
            c3 = *(const f16x8*)(p + 1536);
            cv = cnl[kbase + l4];
        }

#pragma unroll 2
        for (int s = 0; s < 32; ++s) {
            f16x8 p0 = c0, p1 = c1, p2 = c2, p3 = c3; float pv = cv;
            if (s < 31) {   // prefetch next stage (hidden under MFMAs)
                const _Float16* p = fb + (size_t)(s + 1) * 2048 + lane * 8;
                c0 = *(const f16x8*)(p);
                c1 = *(const f16x8*)(p + 512);
                c2 = *(const f16x8*)(p + 1024);
                c3 = *(const f16x8*)(p + 1536);
                cv = cnl[kbase + (s + 1) * 16 + l4];
            }
            const int kabs = kbase + s * 16 + l4;
            f32x4 acc[2];
#pragma unroll
            for (int ns = 0; ns < 2; ++ns) acc[ns] = (f32x4){pv, pv, pv, pv};
#pragma unroll
            for (int ns = 0; ns < 2; ++ns) {
                acc[ns] = __builtin_amdgcn_mfma_f32_16x16x32_f16(ah[ns][0], p0, acc[ns], 0, 0, 0);
                acc[ns] = __builtin_amdgcn_mfma_f32_16x16x32_f16(ah[ns][1], p1, acc[ns], 0, 0, 0);
                acc[ns] = __builtin_amdgcn_mfma_f32_16x16x32_f16(ah[ns][0], p2, acc[ns], 0, 0, 0);
                acc[ns] = __builtin_amdgcn_mfma_f32_16x16x32_f16(ah[ns][1], p3, acc[ns], 0, 0, 0);
                acc[ns] = __builtin_amdgcn_mfma_f32_16x16x32_f16(al[ns][0], p0, acc[ns], 0, 0, 0);
                acc[ns] = __builtin_amdgcn_mfma_f32_16x16x32_f16(al[ns][1], p1, acc[ns], 0, 0, 0);
            }
#pragma unroll
            for (int ns = 0; ns < 2; ++ns)
#pragma unroll
                for (int j = 0; j < 4; ++j) {
                    float sc = acc[ns][j];
                    bool lt = sc < minv[ns][j];
                    minv[ns][j] = lt ? sc : minv[ns][j];
                    mini[ns][j] = lt ? kabs : mini[ns][j];
                }
        }

        // reduce over the 16 k-lanes (ties -> lower k)
#pragma unroll
        for (int m = 1; m < 16; m <<= 1) {
#pragma unroll
            for (int ns = 0; ns < 2; ++ns)
#pragma unroll
                for (int j = 0; j < 4; ++j) {
                    float ov = __shfl_xor(minv[ns][j], m, 64);
                    int   oi = __shfl_xor(mini[ns][j], m, 64);
                    if (ov < minv[ns][j] || (ov == minv[ns][j] && oi < mini[ns][j])) {
                        minv[ns][j] = ov; mini[ns][j] = oi;
                    }
                }
        }
        if (l4 == 0) {
#pragma unroll
            for (int ns = 0; ns < 2; ++ns)
#pragma unroll
                for (int j = 0; j < 4; ++j) {
                    int row = ns * 16 + l16 * 4 + j;   // C/D: row=(lane>>4)*4+reg
                    mv_lds[kq][row] = minv[ns][j];
                    mi_lds[kq][row] = mini[ns][j];
                }
        }
        __syncthreads();
        if (tid < 32) {   // combine 4 quarters ascending (tie -> lower k)
            float bv = mv_lds[0][tid]; int bi = mi_lds[0][tid];
#pragma unroll
            for (int q = 1; q < 4; ++q) {
                float v = mv_lds[q][tid];
                if (v < bv) { bv = v; bi = mi_lds[q][tid]; }
            }
            ks_lds[tid] = bi;
        }
        __syncthreads();

        // r -= cb[k*]  (exact fp32, rows L2-hot)
        {
            int row = tid >> 3, dc = (tid & 7) * 8;
            int kw = ks_lds[row];
            const float* qp = cbl_g + (size_t)kw * ND + dc;
#pragma unroll
            for (int i = 0; i < 2; ++i) {
                float4 q  = *(const float4*)(qp + i * 4);
                float* rp = &r_lds[row][dc + i * 4];
                float4 rv = *(float4*)rp;
                rv.x -= q.x; rv.y -= q.y; rv.z -= q.z; rv.w -= q.w;
                *(float4*)rp = rv;
            }
        }
        __syncthreads();
    }

    // out = x - r_final
    float* ob = out + ((size_t)(b * NC + g * ND)) * NHW + n0;
#pragma unroll
    for (int dd = 0; dd < 2; ++dd) {
        int d = (tid >> 3) + dd * 32;
        int n = (tid & 7) * 4;
        float4 xv = *(const float4*)(&xb[(size_t)d * NHW + n]);
        float4 ov;
        ov.x = xv.x - r_lds[n + 0][d];
        ov.y = xv.y - r_lds[n + 1][d];
        ov.z = xv.z - r_lds[n + 2][d];
        ov.w = xv.w - r_lds[n + 3][d];
        *(float4*)(&ob[(size_t)d * NHW + n]) = ov;
    }
}

// ---------------- fallback path (round-2 kernels, 128 KB ws) ----------------
__global__ void cq_cnorm_kernel(const float* __restrict__ cb, float* __restrict__ cn) {
    int idx = blockIdx.x * 256 + threadIdx.x;
    const float4* p = reinterpret_cast<const float4*>(cb + (size_t)idx * ND);
    float s = 0.f;
#pragma unroll
    for (int i = 0; i < ND / 4; ++i) {
        float4 v = p[i];
        s += v.x * v.x + v.y * v.y + v.z * v.z + v.w * v.w;
    }
    cn[idx] = 0.5f * s;
}

__global__ __launch_bounds__(256, 1) void cq_main_kernel(
    const float* __restrict__ x, const float* __restrict__ cb,
    const float* __restrict__ cn, float* __restrict__ out)
{
    __shared__ float    r_lds[128][RS];
    __shared__ _Float16 cbh_lds[2][128][CS];
    __shared__ _Float16 cbl_lds[2][128][CS];
    __shared__ float    mv_lds[2][128];
    __shared__ int      mi_lds[2][128];
    __shared__ int      ks_lds[128];

    const int tid = threadIdx.x;
    const int blk = blockIdx.x;
    const int nt  = blk & 7;
    const int bg  = blk >> 3;
    const int g   = bg & 3;
    const int b   = bg >> 2;
    const int n0  = nt * 128;

    const float* xb = x + ((size_t)(b * NC + g * ND)) * NHW + n0;
#pragma unroll
    for (int dd = 0; dd < 8; ++dd) {
        int d = (tid >> 5) + dd * 8;
        int n = (tid & 31) * 4;
        float4 xv = *reinterpret_cast<const float4*>(&xb[(size_t)d * NHW + n]);
        r_lds[n + 0][d] = xv.x; r_lds[n + 1][d] = xv.y;
        r_lds[n + 2][d] = xv.z; r_lds[n + 3][d] = xv.w;
    }

    const int lane = tid & 63;
    const int wid  = tid >> 6;
    const int rg   = wid & 1;
    const int kh   = wid >> 1;
    const int l4   = lane & 15;
    const int l16  = lane >> 4;

    __syncthreads();

    for (int l = 0; l < NL; ++l) {
        const float* cbl_g = cb + (size_t)(l * NG + g) * NK * ND;
        const float* cnl   = cn + (size_t)(l * NG + g) * NK;

        f16x8 ah[4][2], al[4][2];
#pragma unroll
        for (int ns = 0; ns < 4; ++ns) {
#pragma unroll
            for (int c = 0; c < 2; ++c) {
                const float* rp = &r_lds[rg * 64 + ns * 16 + l4][c * 32 + l16 * 8];
                float4 v0 = *reinterpret_cast<const float4*>(rp);
                float4 v1 = *reinterpret_cast<const float4*>(rp + 4);
                _Float16 h, lo; f16x8 hv, lv;
                fsplit(-v0.x, h, lo); hv[0] = h; lv[0] = lo;
                fsplit(-v0.y, h, lo); hv[1] = h; lv[1] = lo;
                fsplit(-v0.z, h, lo); hv[2] = h; lv[2] = lo;
                fsplit(-v0.w, h, lo); hv[3] = h; lv[3] = lo;
                fsplit(-v1.x, h, lo); hv[4] = h; lv[4] = lo;
                fsplit(-v1.y, h, lo); hv[5] = h; lv[5] = lo;
                fsplit(-v1.z, h, lo); hv[6] = h; lv[6] = lo;
                fsplit(-v1.w, h, lo); hv[7] = h; lv[7] = lo;
                ah[ns][c] = hv; al[ns][c] = lv;
            }
        }

        float minv[4][4];
        int   mini[4][4];
#pragma unroll
        for (int i = 0; i < 4; ++i)
#pragma unroll
            for (int j = 0; j < 4; ++j) { minv[i][j] = 3.4e38f; mini[i][j] = 0; }

        float4 sreg[8];
#pragma unroll
        for (int p = 0; p < 8; ++p) {
            int kk = p * 16 + (tid >> 4);
            int kg = (kk < 64) ? kk : (1024 - 64 + kk);
            sreg[p] = *reinterpret_cast<const float4*>(&cbl_g[(size_t)kg * ND + (tid & 15) * 4]);
        }
#pragma unroll
        for (int p = 0; p < 8; ++p) {
            int kk = p * 16 + (tid >> 4);
            float4 v = sreg[p];
            _Float16 h, lo; f16x4 hv, lv;
            fsplit(v.x, h, lo); hv[0] = h; lv[0] = lo;
            fsplit(v.y, h, lo); hv[1] = h; lv[1] = lo;
            fsplit(v.z, h, lo); hv[2] = h; lv[2] = lo;
            fsplit(v.w, h, lo); hv[3] = h; lv[3] = lo;
            *reinterpret_cast<f16x4*>(&cbh_lds[0][kk][(tid & 15) * 4]) = hv;
            *reinterpret_cast<f16x4*>(&cbl_lds[0][kk][(tid & 15) * 4]) = lv;
        }

        for (int s = 0; s < 16; ++s) {
            __syncthreads();

            if (s < 15) {
#pragma unroll
                for (int p = 0; p < 8; ++p) {
                    int kk = p * 16 + (tid >> 4);
                    int kg = (kk < 64) ? ((s + 1) * 64 + kk) : (1024 + (s + 1) * 64 + (kk - 64));
                    sreg[p] = *reinterpret_cast<const float4*>(&cbl_g[(size_t)kg * ND + (tid & 15) * 4]);
                }
            }

            const int buf = s & 1;
            for (int ks = 0; ks < 4; ++ks) {
                int lrow = kh * 64 + ks * 16 + l4;
                int kabs = kh * 1024 + s * 64 + ks * 16 + l4;
                f16x8 bh0 = *reinterpret_cast<const f16x8*>(&cbh_lds[buf][lrow][l16 * 8]);
                f16x8 bh1 = *reinterpret_cast<const f16x8*>(&cbh_lds[buf][lrow][32 + l16 * 8]);
                f16x8 bl0 = *reinterpret_cast<const f16x8*>(&cbl_lds[buf][lrow][l16 * 8]);
                f16x8 bl1 = *reinterpret_cast<const f16x8*>(&cbl_lds[buf][lrow][32 + l16 * 8]);
                float cnv = cnl[kabs];
                f32x4 acc[4];
#pragma unroll
                for (int ns = 0; ns < 4; ++ns) acc[ns] = (f32x4){cnv, cnv, cnv, cnv};
#pragma unroll
                for (int ns = 0; ns < 4; ++ns) {
                    acc[ns] = __builtin_amdgcn_mfma_f32_16x16x32_f16(ah[ns][0], bh0, acc[ns], 0, 0, 0);
                    acc[ns] = __builtin_amdgcn_mfma_f32_16x16x32_f16(ah[ns][1], bh1, acc[ns], 0, 0, 0);
                    acc[ns] = __builtin_amdgcn_mfma_f32_16x16x32_f16(ah[ns][0], bl0, acc[ns], 0, 0, 0);
                    acc[ns] = __builtin_amdgcn_mfma_f32_16x16x32_f16(ah[ns][1], bl1, acc[ns], 0, 0, 0);
                    acc[ns] = __builtin_amdgcn_mfma_f32_16x16x32_f16(al[ns][0], bh0, acc[ns], 0, 0, 0);
                    acc[ns] = __builtin_amdgcn_mfma_f32_16x16x32_f16(al[ns][1], bh1, acc[ns], 0, 0, 0);
                }
#pragma unroll
                for (int ns = 0; ns < 4; ++ns)
#pragma unroll
                    for (int j = 0; j < 4; ++j) {
                        float sc = acc[ns][j];
                        bool lt = sc < minv[ns][j];
                        minv[ns][j] = lt ? sc : minv[ns][j];
                        mini[ns][j] = lt ? kabs : mini[ns][j];
                    }
            }

            if (s < 15) {
                const int nbuf = (s + 1) & 1;
#pragma unroll
                for (int p = 0; p < 8; ++p) {
                    int kk = p * 16 + (tid >> 4);
                    float4 v = sreg[p];
                    _Float16 h, lo; f16x4 hv, lv;
                    fsplit(v.x, h, lo); hv[0] = h; lv[0] = lo;
                    fsplit(v.y, h, lo); hv[1] = h; lv[1] = lo;
                    fsplit(v.z, h, lo); hv[2] = h; lv[2] = lo;
                    fsplit(v.w, h, lo); hv[3] = h; lv[3] = lo;
                    *reinterpret_cast<f16x4*>(&cbh_lds[nbuf][kk][(tid & 15) * 4]) = hv;
                    *reinterpret_cast<f16x4*>(&cbl_lds[nbuf][kk][(tid & 15) * 4]) = lv;
                }
            }
        }

#pragma unroll
        for (int m = 1; m < 16; m <<= 1) {
#pragma unroll
            for (int ns = 0; ns < 4; ++ns)
#pragma unroll
                for (int j = 0; j < 4; ++j) {
                    float ov = __shfl_xor(minv[ns][j], m, 64);
                    int   oi = __shfl_xor(mini[ns][j], m, 64);
                    if (ov < minv[ns][j] || (ov == minv[ns][j] && oi < mini[ns][j])) {
                        minv[ns][j] = ov; mini[ns][j] = oi;
                    }
                }
        }
        if (l4 == 0) {
#pragma unroll
            for (int ns = 0; ns < 4; ++ns)
#pragma unroll
                for (int j = 0; j < 4; ++j) {
                    int row = rg * 64 + ns * 16 + l16 * 4 + j;
                    mv_lds[kh][row] = minv[ns][j];
                    mi_lds[kh][row] = mini[ns][j];
                }
        }
        __syncthreads();
        if (tid < 128) {
            float v0 = mv_lds[0][tid], v1 = mv_lds[1][tid];
            ks_lds[tid] = (v1 < v0) ? mi_lds[1][tid] : mi_lds[0][tid];
        }
        __syncthreads();

        {
            int n  = tid >> 1;
            int db = (tid & 1) * 32;
            int kw = ks_lds[n];
            const float* qp = &cbl_g[(size_t)kw * ND + db];
#pragma unroll
            for (int i = 0; i < 8; ++i) {
                float4 q  = *reinterpret_cast<const float4*>(&qp[i * 4]);
                float* rp = &r_lds[n][db + i * 4];
                float4 rv = *reinterpret_cast<float4*>(rp);
                rv.x -= q.x; rv.y -= q.y; rv.z -= q.z; rv.w -= q.w;
                *reinterpret_cast<float4*>(rp) = rv;
            }
        }
        __syncthreads();
    }

    float* ob = out + ((size_t)(b * NC + g * ND)) * NHW + n0;
#pragma unroll
    for (int dd = 0; dd < 8; ++dd) {
        int d = (tid >> 5) + dd * 8;
        int n = (tid & 31) * 4;
        float4 xv = *reinterpret_cast<const float4*>(&xb[(size_t)d * NHW + n]);
        float4 ov;
        ov.x = xv.x - r_lds[n + 0][d];
        ov.y = xv.y - r_lds[n + 1][d];
        ov.z = xv.z - r_lds[n + 2][d];
        ov.w = xv.w - r_lds[n + 3][d];
        *reinterpret_cast<float4*>(&ob[(size_t)d * NHW + n]) = ov;
    }
}

extern "C" void kernel_launch(void* const* d_in, const int* in_sizes, int n_in,
                              void* d_out, int out_size, void* d_ws, size_t ws_size,
                              hipStream_t stream) {
    const float* x  = (const float*)d_in[0];   // [B, C, H, W]
    const float* cb = (const float*)d_in[1];   // [L, G, K, D]
    float* out = (float*)d_out;

    const size_t FRAG_BYTES = (size_t)NL * NG * NK * ND * 2 * 2;  // 8 MiB
    const size_t NEED = FRAG_BYTES + (size_t)NL * NG * NK * 4;    // + cn

    if (ws_size >= NEED) {
        _Float16* wfrag = (_Float16*)d_ws;
        float* cn = (float*)((char*)d_ws + FRAG_BYTES);
        cq_prep_kernel<<<512, 256, 0, stream>>>(cb, wfrag, cn);
        cq_main7_kernel<<<NB * NG * (NHW / 32), 256, 0, stream>>>(x, cb, wfrag, cn, out);
    } else {
        float* cn = (float*)d_ws;
        cq_cnorm_kernel<<<(NL * NG * NK) / 256, 256, 0, stream>>>(cb, cn);
        cq_main_kernel<<<NB * NG * (NHW / 128), 256, 0, stream>>>(x, cb, cn, out);
    }
}